// Round 13
// baseline (286.742 us; speedup 1.0000x reference)
//
#include <hip/hip_runtime.h>
#include <hip/hip_bf16.h>

#define R_DIM 384
#define S_DIM 256
#define M_DIM 256

typedef __attribute__((ext_vector_type(4))) float  f32x4;
typedef __attribute__((ext_vector_type(4))) float  fvec4;
typedef __attribute__((ext_vector_type(8))) short  short8;
typedef __attribute__((ext_vector_type(4))) short  short4v;

__device__ __forceinline__ short f2bf(float f) {
    __hip_bfloat16 h = __float2bfloat16(f);
    return __builtin_bit_cast(short, h);
}
__device__ __forceinline__ float bf2f(short s) {
    return __bfloat162float(__builtin_bit_cast(__hip_bfloat16, s));
}

// async global->LDS, 16B per lane; LDS dest is wave-uniform base + lane*16
__device__ __forceinline__ void gload_lds16(const void* gsrc, void* ldst) {
    __builtin_amdgcn_global_load_lds(
        (const __attribute__((address_space(1))) unsigned int*)gsrc,
        (__attribute__((address_space(3))) unsigned int*)ldst, 16, 0, 0);
}

// SCALE * log2(e): folded into the q-columns of the fused weight so attention
// logits come out of MFMA already in log2 domain.
#define QSCALE (0.17677669529663687f * 1.4426950408889634f)

// ---------------------------------------------------------------------------
// Kernel 0: transpose + convert weights to bf16, k-contiguous rows.
// ---------------------------------------------------------------------------
__global__ __launch_bounds__(256) void k_prep(
    const float* __restrict__ gp, const float* __restrict__ qkvp,
    const float* __restrict__ op, short* __restrict__ Wt1,
    short* __restrict__ Wot)
{
    __shared__ float tile[64][65];
    const int tx = threadIdx.x & 63, ty = threadIdx.x >> 6;
    const int k0 = blockIdx.x * 64;     // 0..3
    const int j0 = blockIdx.y * 64;     // 0..19
    const float* src; int ld, cb;
    if (j0 < 256)       { src = gp;   ld = 256; cb = j0; }
    else if (j0 < 1024) { src = qkvp; ld = 768; cb = j0 - 256; }
    else                { src = op;   ld = 256; cb = j0 - 1024; }
    for (int q = 0; q < 16; ++q) {
        const int kk = q * 4 + ty;
        tile[kk][tx] = src[(k0 + kk) * ld + cb + tx];
    }
    __syncthreads();
    for (int q = 0; q < 16; ++q) {
        const int jj = q * 4 + ty;
        const int jglob = j0 + jj;
        const float scl = (jglob >= 256 && jglob < 512) ? QSCALE : 1.0f;
        const float val = tile[tx][jj] * scl;
        if (jglob < 1024) Wt1[jglob * 256 + k0 + tx] = f2bf(val);
        else              Wot[(jglob - 1024) * 256 + k0 + tx] = f2bf(val);
    }
}

// ---------------------------------------------------------------------------
// Kernel 1: fused gate+qkv projection GEMM, v11 (no A LDS tile at all).
// The A LDS tile existed (since R8) only to fill the af[8][2] register
// fragments once. Each fragment = 8 consecutive msa columns = 32B contiguous
// in global (lane pairs cover 64B lines) -> load DIRECTLY global->register
// at kernel start (overlaps tile-0 B DMA) and convert in-register.
// LDS = B dbuf 16 KB + dedicated V-bounce 18 KB = 34 KB -> 4 blocks/CU,
// 16 waves/CU (R11 was 49 KB -> 3 blocks). Occupancy is the one variable
// this kernel has responded to (18%->31% gave 137->120).
// Sync skeleton byte-identical to R11/R8 (race-free, verified 4 rounds).
// ---------------------------------------------------------------------------
__global__ __launch_bounds__(256, 4) void k_qkvgate(
    const float* __restrict__ msa, const short* __restrict__ Wt1,
    short* __restrict__ gate, short* __restrict__ qb,
    short* __restrict__ kb, short* __restrict__ vb)
{
    __shared__ __align__(16) short Bl[2][128 * 32];  // 2 x 8 KB double buffer
    __shared__ __align__(16) short Tb[128 * 72];     // 18 KB V bounce
    const int tid = threadIdx.x;
    const int l = tid & 63, w = tid >> 6;
    const int wr = w >> 1, wc = w & 1;
    const int rowBase = blockIdx.x * 64;

    // B stage: tile tt covers cols [(tt>>3)*128,+128), k [(tt&7)*32,+32).
    // linear slot L = r*256+w*64+lane; row=L>>2, physical slot=L&3.
    auto stageB = [&](int tt, short* buf) {
        const int cb = (tt >> 3) * 128, k0 = (tt & 7) * 32;
        #pragma unroll
        for (int r = 0; r < 2; ++r) {
            const int L = r * 256 + w * 64 + l;
            const int row = L >> 2, psl = L & 3;
            const int gsl = psl ^ ((row >> 1) & 3);
            gload_lds16(Wt1 + (cb + row) * 256 + k0 + gsl * 8,
                        buf + (r * 256 + w * 64) * 8);
        }
    };

    stageB(0, (short*)Bl[0]);   // issue first; A loads below fill its latency

    // A fragments DIRECT from global, converted in-register (no LDS).
    // af[kc][it]: row i = rowBase + wr*32 + it*16 + (l&15),
    // cols [kc*32 + (l>>4)*8, +8) -> 32B contiguous per lane.
    short8 af[8][2];
    #pragma unroll
    for (int kc = 0; kc < 8; ++kc) {
        #pragma unroll
        for (int it = 0; it < 2; ++it) {
            const int i = rowBase + wr * 32 + it * 16 + (l & 15);
            const int rr = i >> 8, ss = i & 255;
            const float* src = msa + ((ss * R_DIM + rr) << 8) + kc * 32 + (l >> 4) * 8;
            fvec4 v0 = *(const fvec4*)(src);
            fvec4 v1 = *(const fvec4*)(src + 4);
            short8 b;
            b[0] = f2bf(v0.x); b[1] = f2bf(v0.y); b[2] = f2bf(v0.z); b[3] = f2bf(v0.w);
            b[4] = f2bf(v1.x); b[5] = f2bf(v1.y); b[6] = f2bf(v1.z); b[7] = f2bf(v1.w);
            af[kc][it] = b;
        }
    }

    __syncthreads();   // drains own tile-0 DMA (vmcnt(0)) + publishes

    const int rr_blk = rowBase >> 8;
    const int ssBase = rowBase & 255;

    f32x4 acc[2][4] = {};
    for (int ct = 0; ct < 8; ++ct) {
        #pragma unroll
        for (int kc = 0; kc < 8; ++kc) {
            const int t = ct * 8 + kc;
            // issue next-tile DMA at the TOP (full step to fly)
            if (t + 1 < 64) stageB(t + 1, (short*)Bl[(kc + 1) & 1]);

            const short* Bb = (const short*)Bl[kc & 1];
            short8 bfr[4];
            #pragma unroll
            for (int jt = 0; jt < 4; ++jt) {
                const int row = wc * 64 + jt * 16 + (l & 15);
                const int psl = (l >> 4) ^ ((row >> 1) & 3);
                bfr[jt] = *(const short8*)(Bb + row * 32 + psl * 8);
            }
            #pragma unroll
            for (int it = 0; it < 2; ++it)
                #pragma unroll
                for (int jt = 0; jt < 4; ++jt)
                    acc[it][jt] = __builtin_amdgcn_mfma_f32_16x16x32_bf16(
                        af[kc][it], bfr[jt], acc[it][jt], 0, 0, 0);

            // vmcnt(0)+lgkmcnt(0)+barrier: cross-wave-safe publish (R8 form)
            __syncthreads();
        }
        const int colBase = ct * 128;
        const int sel = ct >> 1;  // 0 gate, 1 q, 2 k, 3 v
        if (sel < 3) {
            // gate/q/k epilogue: scatter to [p=(r*8+h)][s][c] (32B segments)
            short* dst = (sel == 0) ? gate : (sel == 1) ? qb : kb;
            #pragma unroll
            for (int it = 0; it < 2; ++it) {
                const int base_i = rowBase + wr * 32 + it * 16 + ((l >> 4) << 2);
                #pragma unroll
                for (int reg = 0; reg < 4; ++reg) {
                    const int i = base_i + reg;
                    const int rr = i >> 8, ss = i & 255;
                    #pragma unroll
                    for (int jt = 0; jt < 4; ++jt) {
                        const int jg = colBase + wc * 64 + jt * 16 + (l & 15);
                        const int jj = jg & 255;
                        const int h = jj >> 5, c = jj & 31;
                        float vv = acc[it][jt][reg];
                        if (sel == 0) vv = 1.0f / (1.0f + __builtin_amdgcn_exp2f(-vv * 1.4426950408889634f));
                        dst[(((rr << 3) + h) * 256 + ss) * 32 + c] = f2bf(vv);
                    }
                }
            }
        } else {
            // V epilogue: bounce-transpose through Tb, then coalesced
            // [p][c][s] stores (16B contiguous per lane).
            const int jjBase = (colBase & 255);   // 0 or 128
            #pragma unroll
            for (int it = 0; it < 2; ++it) {
                const int ssL0 = wr * 32 + it * 16 + ((l >> 4) << 2);
                #pragma unroll
                for (int reg = 0; reg < 4; ++reg) {
                    #pragma unroll
                    for (int jt = 0; jt < 4; ++jt) {
                        const int jjL = wc * 64 + jt * 16 + (l & 15);
                        Tb[jjL * 72 + ssL0 + reg] = f2bf(acc[it][jt][reg]);
                    }
                }
            }
            __syncthreads();
            #pragma unroll
            for (int q = 0; q < 4; ++q) {
                const int cid = q * 256 + tid;     // 1024 16B-chunks
                const int jjL = cid >> 3, sc = cid & 7;
                short8 vv8 = *(const short8*)(&Tb[jjL * 72 + sc * 8]);
                const int jj = jjBase + jjL;
                const int h = jj >> 5, c = jj & 31;
                const int pp = (rr_blk << 3) + h;
                *(short8*)(vb + (pp << 13) + (c << 8) + ssBase + sc * 8) = vv8;
            }
            // next write to Tb is 8 barrier-separated steps away -> safe
        }
        #pragma unroll
        for (int it = 0; it < 2; ++it)
            #pragma unroll
            for (int jt = 0; jt < 4; ++jt)
                acc[it][jt] = (f32x4){0.f, 0.f, 0.f, 0.f};
    }
}

// ---------------------------------------------------------------------------
// Kernel 2: attention per (r,h), v2 — ZERO LDS staging, zero barriers.
// Q/K frags 16B/lane contiguous from [s][c]; V frags 16B/lane contiguous
// from [c][s]. Only LDS: per-wave P buffer. Waves fully independent.
// NO-MAX softmax (logits tiny; shift-invariant), row sums via MFMA vs ones.
// ---------------------------------------------------------------------------
__global__ __launch_bounds__(256) void k_attn(
    short* qo, const short* __restrict__ kb, const short* __restrict__ vb,
    const short* __restrict__ gate)
{
    __shared__ __align__(16) short Pl[4 * 32 * 68];
    const int tid = threadIdx.x;
    const int l = tid & 63, w = tid >> 6;
    const int p = blockIdx.x;
    short* qg = qo + p * 8192;
    const short* kg = kb + p * 8192;
    const short* vg = vb + p * 8192;   // [c][s] layout
    const short* gg = gate + p * 8192;
    const int c0 = (l >> 4) * 8;

    // Q fragments (A-operand) straight from global, read before overwrite
    short8 qf[4];
    #pragma unroll
    for (int it = 0; it < 4; ++it) {
        const int s = w * 64 + it * 16 + (l & 15);
        qf[it] = *(const short8*)(qg + s * 32 + c0);
    }

    f32x4 oacc[4][2] = {};
    f32x4 ssum[4] = {};
    short8 bones;
    #pragma unroll
    for (int e = 0; e < 8; ++e) bones[e] = (short)0x3F80;  // bf16 1.0
    short* Pw = &Pl[w * (32 * 68)];

    for (int ch = 0; ch < 4; ++ch) {
        const int j0 = ch * 64;
        f32x4 sacc[4][4] = {};
        // K fragments (B-operand) straight from global [s][c]
        short8 kf[4];
        #pragma unroll
        for (int jt = 0; jt < 4; ++jt) {
            const int row = j0 + jt * 16 + (l & 15);
            kf[jt] = *(const short8*)(kg + row * 32 + c0);
        }
        #pragma unroll
        for (int it = 0; it < 4; ++it)
            #pragma unroll
            for (int jt = 0; jt < 4; ++jt)
                sacc[it][jt] = __builtin_amdgcn_mfma_f32_16x16x32_bf16(
                    qf[it], kf[jt], sacc[it][jt], 0, 0, 0);

        // V fragments (B-operand) straight from global [c][s]
        short8 vfa[2][2];
        #pragma unroll
        for (int kk = 0; kk < 2; ++kk)
            #pragma unroll
            for (int cti = 0; cti < 2; ++cti)
                vfa[kk][cti] = *(const short8*)(
                    vg + (cti * 16 + (l & 15)) * 256 + j0 + kk * 32 + (l >> 4) * 8);

        #pragma unroll
        for (int ih = 0; ih < 2; ++ih) {
            // P = exp2(logit), bf16, into per-wave half buffer [32][68]
            #pragma unroll
            for (int itl = 0; itl < 2; ++itl) {
                const int it = ih * 2 + itl;
                #pragma unroll
                for (int reg = 0; reg < 4; ++reg) {
                    const int rowl = itl * 16 + ((l >> 4) << 2) + reg;
                    #pragma unroll
                    for (int jt = 0; jt < 4; ++jt)
                        Pw[rowl * 68 + jt * 16 + (l & 15)] =
                            f2bf(__builtin_amdgcn_exp2f(sacc[it][jt][reg]));
                }
            }
            // PV + row-sum MFMAs for this half
            #pragma unroll
            for (int kk = 0; kk < 2; ++kk) {
                const int koff = kk * 32 + (l >> 4) * 8;
                short8 pf[2];
                #pragma unroll
                for (int itl = 0; itl < 2; ++itl)
                    pf[itl] = *(const short8*)(&Pw[(itl * 16 + (l & 15)) * 68 + koff]);
                #pragma unroll
                for (int itl = 0; itl < 2; ++itl) {
                    const int it = ih * 2 + itl;
                    #pragma unroll
                    for (int cti = 0; cti < 2; ++cti)
                        oacc[it][cti] = __builtin_amdgcn_mfma_f32_16x16x32_bf16(
                            pf[itl], vfa[kk][cti], oacc[it][cti], 0, 0, 0);
                    ssum[it] = __builtin_amdgcn_mfma_f32_16x16x32_bf16(
                        pf[itl], bones, ssum[it], 0, 0, 0);
                }
            }
        }
    }
    // epilogue: normalize, gate, write in place over q
    #pragma unroll
    for (int it = 0; it < 4; ++it) {
        #pragma unroll
        for (int reg = 0; reg < 4; ++reg) {
            const float inv = 1.0f / ssum[it][reg];
            const int s = w * 64 + it * 16 + ((l >> 4) << 2) + reg;
            #pragma unroll
            for (int cti = 0; cti < 2; ++cti) {
                const int c = cti * 16 + (l & 15);
                const float gv = bf2f(gg[s * 32 + c]);
                qg[s * 32 + c] = f2bf(oacc[it][cti][reg] * inv * gv);
            }
        }
    }
}

// ---------------------------------------------------------------------------
// Kernel 3: output projection GEMM + un-transpose to [N,S,R,M] fp32.
// ---------------------------------------------------------------------------
__global__ __launch_bounds__(256) void k_out(
    const short* __restrict__ ao, const short* __restrict__ Wot,
    float* __restrict__ out)
{
    __shared__ __align__(16) char Al[128 * 128];
    __shared__ __align__(16) char Bl[128 * 128];
    const int tid = threadIdx.x;
    const int l = tid & 63, w = tid >> 6;
    const int wr = w >> 1, wc = w & 1;
    const int rowBase = blockIdx.y * 128;
    const int colBase = blockIdx.x * 128;
    f32x4 acc[4][4] = {};
    for (int kidx = 0; kidx < 4; ++kidx) {
        const int k0 = kidx * 64;
        {
            const int slot = tid & 7;
            const int rb = tid >> 3;
            const int kin = k0 + slot * 8;
            const int h = kin >> 5, c0 = kin & 31;
            #pragma unroll
            for (int ii = 0; ii < 4; ++ii) {
                const int a_r = ii * 32 + rb;
                const int i = rowBase + a_r;
                const int rr = i >> 8, ss = i & 255;
                short8 av = *(const short8*)(ao + (((rr << 3) + h) * 256 + ss) * 32 + c0);
                *(short8*)(Al + a_r * 128 + ((slot ^ (a_r & 7)) << 4)) = av;
            }
            #pragma unroll
            for (int jj = 0; jj < 4; ++jj) {
                const int j_r = jj * 32 + rb;
                short8 wv = *(const short8*)(Wot + (colBase + j_r) * 256 + k0 + slot * 8);
                *(short8*)(Bl + j_r * 128 + ((slot ^ (j_r & 7)) << 4)) = wv;
            }
        }
        __syncthreads();
        #pragma unroll
        for (int kh = 0; kh < 2; ++kh) {
            short8 af[4], bfr[4];
            const int sl = kh * 4 + (l >> 4);
            #pragma unroll
            for (int it = 0; it < 4; ++it) {
                const int row = wr * 64 + it * 16 + (l & 15);
                af[it] = *(const short8*)(Al + row * 128 + ((sl ^ (row & 7)) << 4));
            }
            #pragma unroll
            for (int jt = 0; jt < 4; ++jt) {
                const int row = wc * 64 + jt * 16 + (l & 15);
                bfr[jt] = *(const short8*)(Bl + row * 128 + ((sl ^ (row & 7)) << 4));
            }
            #pragma unroll
            for (int it = 0; it < 4; ++it)
                #pragma unroll
                for (int jt = 0; jt < 4; ++jt)
                    acc[it][jt] = __builtin_amdgcn_mfma_f32_16x16x32_bf16(
                        af[it], bfr[jt], acc[it][jt], 0, 0, 0);
        }
        __syncthreads();
    }
    #pragma unroll
    for (int it = 0; it < 4; ++it) {
        const int base_i = rowBase + wr * 64 + it * 16 + ((l >> 4) << 2);
        #pragma unroll
        for (int reg = 0; reg < 4; ++reg) {
            const int i = base_i + reg;
            const int rr = i >> 8, ss = i & 255;
            #pragma unroll
            for (int jt = 0; jt < 4; ++jt) {
                const int m = colBase + wc * 64 + jt * 16 + (l & 15);
                out[((ss * R_DIM + rr) << 8) + m] = acc[it][jt][reg];
            }
        }
    }
}

// ---------------------------------------------------------------------------
extern "C" void kernel_launch(void* const* d_in, const int* in_sizes, int n_in,
                              void* d_out, int out_size, void* d_ws, size_t ws_size,
                              hipStream_t stream) {
    const float* msa  = (const float*)d_in[0];
    const float* gp   = (const float*)d_in[1];
    const float* qkvp = (const float*)d_in[2];
    const float* op   = (const float*)d_in[3];
    float* out = (float*)d_out;
    char* ws = (char*)d_ws;

    const size_t SZ = 50331648;  // 98304*256*2 bytes (one bf16 activation tensor)
    short* Wt1  = (short*)ws;                        // 1024x256 bf16 (512 KB)
    short* Wot  = (short*)(ws + 524288);             // 256x256 bf16 (128 KB)
    short* gate = (short*)(ws + 655360);
    short* qb   = (short*)(ws + 655360 + 1 * SZ);
    short* kb   = (short*)(ws + 655360 + 2 * SZ);
    short* vb   = (short*)(ws + 655360 + 3 * SZ);

    k_prep<<<dim3(4, 20), 256, 0, stream>>>(gp, qkvp, op, Wt1, Wot);
    k_qkvgate<<<dim3(1536), 256, 0, stream>>>(msa, Wt1, gate, qb, kb, vb);
    k_attn<<<dim3(3072), 256, 0, stream>>>(qb, kb, vb, gate);
    k_out<<<dim3(2, 768), 256, 0, stream>>>(qb, Wot, out);
}

// Round 14
// 221.955 us; speedup vs baseline: 1.2919x; 1.2919x over previous
//
#include <hip/hip_runtime.h>
#include <hip/hip_bf16.h>

#define R_DIM 384
#define S_DIM 256
#define M_DIM 256

typedef __attribute__((ext_vector_type(4))) float  f32x4;
typedef __attribute__((ext_vector_type(4))) float  fvec4;
typedef __attribute__((ext_vector_type(8))) short  short8;
typedef __attribute__((ext_vector_type(4))) short  short4v;

__device__ __forceinline__ short f2bf(float f) {
    __hip_bfloat16 h = __float2bfloat16(f);
    return __builtin_bit_cast(short, h);
}
__device__ __forceinline__ float bf2f(short s) {
    return __bfloat162float(__builtin_bit_cast(__hip_bfloat16, s));
}

// async global->LDS, 16B per lane; LDS dest is wave-uniform base + lane*16
__device__ __forceinline__ void gload_lds16(const void* gsrc, void* ldst) {
    __builtin_amdgcn_global_load_lds(
        (const __attribute__((address_space(1))) unsigned int*)gsrc,
        (__attribute__((address_space(3))) unsigned int*)ldst, 16, 0, 0);
}

// SCALE * log2(e): folded into the q-columns of the fused weight so attention
// logits come out of MFMA already in log2 domain.
#define QSCALE (0.17677669529663687f * 1.4426950408889634f)

// ---------------------------------------------------------------------------
// Kernel 0: transpose + convert weights to bf16, k-contiguous rows.
// ---------------------------------------------------------------------------
__global__ __launch_bounds__(256) void k_prep(
    const float* __restrict__ gp, const float* __restrict__ qkvp,
    const float* __restrict__ op, short* __restrict__ Wt1,
    short* __restrict__ Wot)
{
    __shared__ float tile[64][65];
    const int tx = threadIdx.x & 63, ty = threadIdx.x >> 6;
    const int k0 = blockIdx.x * 64;     // 0..3
    const int j0 = blockIdx.y * 64;     // 0..19
    const float* src; int ld, cb;
    if (j0 < 256)       { src = gp;   ld = 256; cb = j0; }
    else if (j0 < 1024) { src = qkvp; ld = 768; cb = j0 - 256; }
    else                { src = op;   ld = 256; cb = j0 - 1024; }
    for (int q = 0; q < 16; ++q) {
        const int kk = q * 4 + ty;
        tile[kk][tx] = src[(k0 + kk) * ld + cb + tx];
    }
    __syncthreads();
    for (int q = 0; q < 16; ++q) {
        const int jj = q * 4 + ty;
        const int jglob = j0 + jj;
        const float scl = (jglob >= 256 && jglob < 512) ? QSCALE : 1.0f;
        const float val = tile[tx][jj] * scl;
        if (jglob < 1024) Wt1[jglob * 256 + k0 + tx] = f2bf(val);
        else              Wot[(jglob - 1024) * 256 + k0 + tx] = f2bf(val);
    }
}

// ---------------------------------------------------------------------------
// Kernel 1: fused gate+qkv projection GEMM, v9 (R11 — local optimum, frozen).
// A-tile staged once to LDS -> af[8][2] register hoist; B dbuf via
// global_load_lds, stage-at-top / __syncthreads-at-bottom (race-free R8
// skeleton); V epilogue bounce-transposed through dead Al for coalesced
// [p][c][s] stores. 6 structural variants on either side all lost (R2,R5,
// R6,R12,R13) — do not touch.
// ---------------------------------------------------------------------------
__global__ __launch_bounds__(256, 3) void k_qkvgate(
    const float* __restrict__ msa, const short* __restrict__ Wt1,
    short* __restrict__ gate, short* __restrict__ qb,
    short* __restrict__ kb, short* __restrict__ vb)
{
    __shared__ __align__(16) char Al[64 * 512];      // 32 KB; dead after hoist
    __shared__ __align__(16) short Bl[2][128 * 32];  // 2 x 8 KB double buffer
    const int tid = threadIdx.x;
    const int l = tid & 63, w = tid >> 6;
    const int wr = w >> 1, wc = w & 1;
    const int rowBase = blockIdx.x * 64;

    // stage A once: fp32 -> bf16 (16 iters, 64 rows)
    {
        const int arow0 = tid >> 6;          // 0..3
        const int col4  = (tid & 63) * 4;    // 0..252
        const int slot  = (tid & 63) >> 1;   // 16B slot 0..31
        const int sub   = (tid & 63) & 1;    // which 8B half
        for (int ii = 0; ii < 16; ++ii) {
            const int a_r = ii * 4 + arow0;
            const int i = rowBase + a_r;
            const int rr = i >> 8, ss = i & 255;
            fvec4 vv = *(const fvec4*)(msa + ((ss * R_DIM + rr) << 8) + col4);
            short4v b4;
            b4.x = f2bf(vv.x); b4.y = f2bf(vv.y);
            b4.z = f2bf(vv.z); b4.w = f2bf(vv.w);
            *(short4v*)(Al + a_r * 512 + ((slot ^ (a_r & 7)) << 4) + sub * 8) = b4;
        }
    }

    // B stage: tile tt covers cols [(tt>>3)*128,+128), k [(tt&7)*32,+32).
    auto stageB = [&](int tt, short* buf) {
        const int cb = (tt >> 3) * 128, k0 = (tt & 7) * 32;
        #pragma unroll
        for (int r = 0; r < 2; ++r) {
            const int L = r * 256 + w * 64 + l;
            const int row = L >> 2, psl = L & 3;
            const int gsl = psl ^ ((row >> 1) & 3);
            gload_lds16(Wt1 + (cb + row) * 256 + k0 + gsl * 8,
                        buf + (r * 256 + w * 64) * 8);
        }
    };

    stageB(0, (short*)Bl[0]);
    __syncthreads();   // drains the tile-0 DMA for ALL waves, then publishes

    // hoist ALL A fragments to registers (static indices only); Al dead after
    short8 af[8][2];
    #pragma unroll
    for (int kc = 0; kc < 8; ++kc) {
        const int aslot = kc * 4 + (l >> 4);
        #pragma unroll
        for (int it = 0; it < 2; ++it) {
            const int row = wr * 32 + it * 16 + (l & 15);
            af[kc][it] = *(const short8*)(Al + row * 512 + ((aslot ^ (row & 7)) << 4));
        }
    }

    short* AlT = (short*)Al;   // reuse as [128 jj][72 ss] bounce (18.4 KB)
    const int rr_blk = rowBase >> 8;
    const int ssBase = rowBase & 255;

    f32x4 acc[2][4] = {};
    for (int ct = 0; ct < 8; ++ct) {
        #pragma unroll
        for (int kc = 0; kc < 8; ++kc) {
            const int t = ct * 8 + kc;
            // issue next-tile DMA at the TOP (full step to fly)
            if (t + 1 < 64) stageB(t + 1, (short*)Bl[(kc + 1) & 1]);

            const short* Bb = (const short*)Bl[kc & 1];
            short8 bfr[4];
            #pragma unroll
            for (int jt = 0; jt < 4; ++jt) {
                const int row = wc * 64 + jt * 16 + (l & 15);
                const int psl = (l >> 4) ^ ((row >> 1) & 3);
                bfr[jt] = *(const short8*)(Bb + row * 32 + psl * 8);
            }
            #pragma unroll
            for (int it = 0; it < 2; ++it)
                #pragma unroll
                for (int jt = 0; jt < 4; ++jt)
                    acc[it][jt] = __builtin_amdgcn_mfma_f32_16x16x32_bf16(
                        af[kc][it], bfr[jt], acc[it][jt], 0, 0, 0);

            // vmcnt(0)+lgkmcnt(0)+barrier: cross-wave-safe publish
            __syncthreads();
        }
        const int colBase = ct * 128;
        const int sel = ct >> 1;  // 0 gate, 1 q, 2 k, 3 v
        if (sel < 3) {
            // gate/q/k epilogue: scatter to [p=(r*8+h)][s][c] (32B segments)
            short* dst = (sel == 0) ? gate : (sel == 1) ? qb : kb;
            #pragma unroll
            for (int it = 0; it < 2; ++it) {
                const int base_i = rowBase + wr * 32 + it * 16 + ((l >> 4) << 2);
                #pragma unroll
                for (int reg = 0; reg < 4; ++reg) {
                    const int i = base_i + reg;
                    const int rr = i >> 8, ss = i & 255;
                    #pragma unroll
                    for (int jt = 0; jt < 4; ++jt) {
                        const int jg = colBase + wc * 64 + jt * 16 + (l & 15);
                        const int jj = jg & 255;
                        const int h = jj >> 5, c = jj & 31;
                        float vv = acc[it][jt][reg];
                        if (sel == 0) vv = 1.0f / (1.0f + __builtin_amdgcn_exp2f(-vv * 1.4426950408889634f));
                        dst[(((rr << 3) + h) * 256 + ss) * 32 + c] = f2bf(vv);
                    }
                }
            }
        } else {
            // V epilogue: bounce-transpose through dead Al, then coalesced
            // [p][c][s] stores (16B contiguous per lane).
            const int jjBase = (colBase & 255);   // 0 or 128
            #pragma unroll
            for (int it = 0; it < 2; ++it) {
                const int ssL0 = wr * 32 + it * 16 + ((l >> 4) << 2);
                #pragma unroll
                for (int reg = 0; reg < 4; ++reg) {
                    #pragma unroll
                    for (int jt = 0; jt < 4; ++jt) {
                        const int jjL = wc * 64 + jt * 16 + (l & 15);
                        AlT[jjL * 72 + ssL0 + reg] = f2bf(acc[it][jt][reg]);
                    }
                }
            }
            __syncthreads();
            #pragma unroll
            for (int q = 0; q < 4; ++q) {
                const int cid = q * 256 + tid;     // 1024 16B-chunks
                const int jjL = cid >> 3, sc = cid & 7;
                short8 vv8 = *(const short8*)(&AlT[jjL * 72 + sc * 8]);
                const int jj = jjBase + jjL;
                const int h = jj >> 5, c = jj & 31;
                const int pp = (rr_blk << 3) + h;
                *(short8*)(vb + (pp << 13) + (c << 8) + ssBase + sc * 8) = vv8;
            }
            // next use of AlT is 8 barrier-separated steps away -> safe
        }
        #pragma unroll
        for (int it = 0; it < 2; ++it)
            #pragma unroll
            for (int jt = 0; jt < 4; ++jt)
                acc[it][jt] = (f32x4){0.f, 0.f, 0.f, 0.f};
    }
}

// ---------------------------------------------------------------------------
// Kernel 2: attention per (r,h), v2 — ZERO LDS staging, zero barriers.
// Q/K frags 16B/lane contiguous from [s][c]; V frags 16B/lane contiguous
// from [c][s]. Only LDS: per-wave P buffer. Waves fully independent.
// NO-MAX softmax (logits tiny; shift-invariant), row sums via MFMA vs ones.
// ---------------------------------------------------------------------------
__global__ __launch_bounds__(256) void k_attn(
    short* qo, const short* __restrict__ kb, const short* __restrict__ vb,
    const short* __restrict__ gate)
{
    __shared__ __align__(16) short Pl[4 * 32 * 68];
    const int tid = threadIdx.x;
    const int l = tid & 63, w = tid >> 6;
    const int p = blockIdx.x;
    short* qg = qo + p * 8192;
    const short* kg = kb + p * 8192;
    const short* vg = vb + p * 8192;   // [c][s] layout
    const short* gg = gate + p * 8192;
    const int c0 = (l >> 4) * 8;

    // Q fragments (A-operand) straight from global, read before overwrite
    short8 qf[4];
    #pragma unroll
    for (int it = 0; it < 4; ++it) {
        const int s = w * 64 + it * 16 + (l & 15);
        qf[it] = *(const short8*)(qg + s * 32 + c0);
    }

    f32x4 oacc[4][2] = {};
    f32x4 ssum[4] = {};
    short8 bones;
    #pragma unroll
    for (int e = 0; e < 8; ++e) bones[e] = (short)0x3F80;  // bf16 1.0
    short* Pw = &Pl[w * (32 * 68)];

    for (int ch = 0; ch < 4; ++ch) {
        const int j0 = ch * 64;
        f32x4 sacc[4][4] = {};
        // K fragments (B-operand) straight from global [s][c]
        short8 kf[4];
        #pragma unroll
        for (int jt = 0; jt < 4; ++jt) {
            const int row = j0 + jt * 16 + (l & 15);
            kf[jt] = *(const short8*)(kg + row * 32 + c0);
        }
        #pragma unroll
        for (int it = 0; it < 4; ++it)
            #pragma unroll
            for (int jt = 0; jt < 4; ++jt)
                sacc[it][jt] = __builtin_amdgcn_mfma_f32_16x16x32_bf16(
                    qf[it], kf[jt], sacc[it][jt], 0, 0, 0);

        // V fragments (B-operand) straight from global [c][s]
        short8 vfa[2][2];
        #pragma unroll
        for (int kk = 0; kk < 2; ++kk)
            #pragma unroll
            for (int cti = 0; cti < 2; ++cti)
                vfa[kk][cti] = *(const short8*)(
                    vg + (cti * 16 + (l & 15)) * 256 + j0 + kk * 32 + (l >> 4) * 8);

        #pragma unroll
        for (int ih = 0; ih < 2; ++ih) {
            // P = exp2(logit), bf16, into per-wave half buffer [32][68]
            #pragma unroll
            for (int itl = 0; itl < 2; ++itl) {
                const int it = ih * 2 + itl;
                #pragma unroll
                for (int reg = 0; reg < 4; ++reg) {
                    const int rowl = itl * 16 + ((l >> 4) << 2) + reg;
                    #pragma unroll
                    for (int jt = 0; jt < 4; ++jt)
                        Pw[rowl * 68 + jt * 16 + (l & 15)] =
                            f2bf(__builtin_amdgcn_exp2f(sacc[it][jt][reg]));
                }
            }
            // PV + row-sum MFMAs for this half
            #pragma unroll
            for (int kk = 0; kk < 2; ++kk) {
                const int koff = kk * 32 + (l >> 4) * 8;
                short8 pf[2];
                #pragma unroll
                for (int itl = 0; itl < 2; ++itl)
                    pf[itl] = *(const short8*)(&Pw[(itl * 16 + (l & 15)) * 68 + koff]);
                #pragma unroll
                for (int itl = 0; itl < 2; ++itl) {
                    const int it = ih * 2 + itl;
                    #pragma unroll
                    for (int cti = 0; cti < 2; ++cti)
                        oacc[it][cti] = __builtin_amdgcn_mfma_f32_16x16x32_bf16(
                            pf[itl], vfa[kk][cti], oacc[it][cti], 0, 0, 0);
                    ssum[it] = __builtin_amdgcn_mfma_f32_16x16x32_bf16(
                        pf[itl], bones, ssum[it], 0, 0, 0);
                }
            }
        }
    }
    // epilogue: normalize, gate, write in place over q
    #pragma unroll
    for (int it = 0; it < 4; ++it) {
        #pragma unroll
        for (int reg = 0; reg < 4; ++reg) {
            const float inv = 1.0f / ssum[it][reg];
            const int s = w * 64 + it * 16 + ((l >> 4) << 2) + reg;
            #pragma unroll
            for (int cti = 0; cti < 2; ++cti) {
                const int c = cti * 16 + (l & 15);
                const float gv = bf2f(gg[s * 32 + c]);
                qg[s * 32 + c] = f2bf(oacc[it][cti][reg] * inv * gv);
            }
        }
    }
}

// ---------------------------------------------------------------------------
// Kernel 3: output projection GEMM + un-transpose, v2.
// A-frags DIRECT from global ao[p][s][c] (16B/lane; wave covers 16 full 64B
// lines — same verified pattern as k_attn's Q loads). B (Wot, 128 KB,
// L2-hot) via the R8/R11-verified global_load_lds dbuf skeleton. No A
// staging pass; LDS 16 KB; one barrier per k-step.
// ---------------------------------------------------------------------------
__global__ __launch_bounds__(256, 4) void k_out(
    const short* __restrict__ ao, const short* __restrict__ Wot,
    float* __restrict__ out)
{
    __shared__ __align__(16) short Bl[2][128 * 32];  // 2 x 8 KB double buffer
    const int tid = threadIdx.x;
    const int l = tid & 63, w = tid >> 6;
    const int wr = w >> 1, wc = w & 1;
    const int rowBase = blockIdx.y * 128;
    const int colBase = blockIdx.x * 128;

    auto stageB = [&](int kc, short* buf) {
        const int k0 = kc * 32;
        #pragma unroll
        for (int r = 0; r < 2; ++r) {
            const int L = r * 256 + w * 64 + l;
            const int row = L >> 2, psl = L & 3;
            const int gsl = psl ^ ((row >> 1) & 3);
            gload_lds16(Wot + (colBase + row) * 256 + k0 + gsl * 8,
                        buf + (r * 256 + w * 64) * 8);
        }
    };

    stageB(0, (short*)Bl[0]);
    __syncthreads();   // drain own tile-0 DMA + publish

    f32x4 acc[4][4] = {};
    #pragma unroll
    for (int kc = 0; kc < 8; ++kc) {
        if (kc + 1 < 8) stageB(kc + 1, (short*)Bl[(kc + 1) & 1]);

        // A fragments direct from global: col jj = kc*32+(l>>4)*8 -> h=kc
        short8 af[4];
        #pragma unroll
        for (int it = 0; it < 4; ++it) {
            const int i = rowBase + wr * 64 + it * 16 + (l & 15);
            const int rr = i >> 8, ss = i & 255;
            af[it] = *(const short8*)(ao + (((rr << 3) + kc) * 256 + ss) * 32 + (l >> 4) * 8);
        }
        const short* Bb = (const short*)Bl[kc & 1];
        short8 bfr[4];
        #pragma unroll
        for (int jt = 0; jt < 4; ++jt) {
            const int row = wc * 64 + jt * 16 + (l & 15);
            const int psl = (l >> 4) ^ ((row >> 1) & 3);
            bfr[jt] = *(const short8*)(Bb + row * 32 + psl * 8);
        }
        #pragma unroll
        for (int it = 0; it < 4; ++it)
            #pragma unroll
            for (int jt = 0; jt < 4; ++jt)
                acc[it][jt] = __builtin_amdgcn_mfma_f32_16x16x32_bf16(
                    af[it], bfr[jt], acc[it][jt], 0, 0, 0);

        __syncthreads();   // vmcnt(0)+lgkmcnt(0)+barrier: race-free publish
    }
    #pragma unroll
    for (int it = 0; it < 4; ++it) {
        const int base_i = rowBase + wr * 64 + it * 16 + ((l >> 4) << 2);
        #pragma unroll
        for (int reg = 0; reg < 4; ++reg) {
            const int i = base_i + reg;
            const int rr = i >> 8, ss = i & 255;
            #pragma unroll
            for (int jt = 0; jt < 4; ++jt) {
                const int m = colBase + wc * 64 + jt * 16 + (l & 15);
                out[((ss * R_DIM + rr) << 8) + m] = acc[it][jt][reg];
            }
        }
    }
}

// ---------------------------------------------------------------------------
extern "C" void kernel_launch(void* const* d_in, const int* in_sizes, int n_in,
                              void* d_out, int out_size, void* d_ws, size_t ws_size,
                              hipStream_t stream) {
    const float* msa  = (const float*)d_in[0];
    const float* gp   = (const float*)d_in[1];
    const float* qkvp = (const float*)d_in[2];
    const float* op   = (const float*)d_in[3];
    float* out = (float*)d_out;
    char* ws = (char*)d_ws;

    const size_t SZ = 50331648;  // 98304*256*2 bytes (one bf16 activation tensor)
    short* Wt1  = (short*)ws;                        // 1024x256 bf16 (512 KB)
    short* Wot  = (short*)(ws + 524288);             // 256x256 bf16 (128 KB)
    short* gate = (short*)(ws + 655360);
    short* qb   = (short*)(ws + 655360 + 1 * SZ);
    short* kb   = (short*)(ws + 655360 + 2 * SZ);
    short* vb   = (short*)(ws + 655360 + 3 * SZ);

    k_prep<<<dim3(4, 20), 256, 0, stream>>>(gp, qkvp, op, Wt1, Wot);
    k_qkvgate<<<dim3(1536), 256, 0, stream>>>(msa, Wt1, gate, qb, kb, vb);
    k_attn<<<dim3(3072), 256, 0, stream>>>(qb, kb, vb, gate);
    k_out<<<dim3(2, 768), 256, 0, stream>>>(qb, Wot, out);
}

// Round 17
// 220.741 us; speedup vs baseline: 1.2990x; 1.0055x over previous
//
#include <hip/hip_runtime.h>
#include <hip/hip_bf16.h>

#define R_DIM 384
#define S_DIM 256
#define M_DIM 256

typedef __attribute__((ext_vector_type(4))) float  f32x4;
typedef __attribute__((ext_vector_type(4))) float  fvec4;
typedef __attribute__((ext_vector_type(8))) short  short8;
typedef __attribute__((ext_vector_type(4))) short  short4v;
typedef __attribute__((ext_vector_type(2))) int    i32x2;

__device__ __forceinline__ short f2bf(float f) {
    __hip_bfloat16 h = __float2bfloat16(f);
    return __builtin_bit_cast(short, h);
}
__device__ __forceinline__ float bf2f(short s) {
    return __bfloat162float(__builtin_bit_cast(__hip_bfloat16, s));
}

// v_mfma_f32_16x16x16_bf16 (K=16): A/B = 4 bf16 (2 VGPR), C/D = 4 f32.
// Layout: A[row=l&15][k=(l>>4)*4+e], B[k=(l>>4)*4+e][col=l&15],
//         D[row=(l>>4)*4+reg][col=l&15].
// R16's raw asm ("=v", no early-clobber) let the allocator overlap the D
// tuple with A/B sources -> UB (MFMA writes D incrementally while reading
// A/B across passes) -> NaN. Use the carried-forward builtin when present
// (compiler models constraints+hazards); else early-clobber asm + nops.
#if __has_builtin(__builtin_amdgcn_mfma_f32_16x16x16bf16_1k)
__device__ __forceinline__ f32x4 mfma16(short4v a, short4v b, f32x4 c) {
    return __builtin_amdgcn_mfma_f32_16x16x16bf16_1k(a, b, c, 0, 0, 0);
}
#else
__device__ __forceinline__ f32x4 mfma16(short4v a, short4v b, f32x4 c) {
    f32x4 d;
    asm volatile("v_mfma_f32_16x16x16_bf16 %0, %1, %2, %3\n\t"
                 "s_nop 7\n\ts_nop 7"
                 : "=&v"(d) : "v"(a), "v"(b), "v"(c));
    return d;
}
#endif

// async global->LDS, 16B per lane; LDS dest is wave-uniform base + lane*16
__device__ __forceinline__ void gload_lds16(const void* gsrc, void* ldst) {
    __builtin_amdgcn_global_load_lds(
        (const __attribute__((address_space(1))) unsigned int*)gsrc,
        (__attribute__((address_space(3))) unsigned int*)ldst, 16, 0, 0);
}

// SCALE * log2(e): folded into the q-columns of the fused weight so attention
// logits come out of MFMA already in log2 domain.
#define QSCALE (0.17677669529663687f * 1.4426950408889634f)

// ---------------------------------------------------------------------------
// Kernel 0: transpose + convert weights to bf16, k-contiguous rows.
// ---------------------------------------------------------------------------
__global__ __launch_bounds__(256) void k_prep(
    const float* __restrict__ gp, const float* __restrict__ qkvp,
    const float* __restrict__ op, short* __restrict__ Wt1,
    short* __restrict__ Wot)
{
    __shared__ float tile[64][65];
    const int tx = threadIdx.x & 63, ty = threadIdx.x >> 6;
    const int k0 = blockIdx.x * 64;     // 0..3
    const int j0 = blockIdx.y * 64;     // 0..19
    const float* src; int ld, cb;
    if (j0 < 256)       { src = gp;   ld = 256; cb = j0; }
    else if (j0 < 1024) { src = qkvp; ld = 768; cb = j0 - 256; }
    else                { src = op;   ld = 256; cb = j0 - 1024; }
    for (int q = 0; q < 16; ++q) {
        const int kk = q * 4 + ty;
        tile[kk][tx] = src[(k0 + kk) * ld + cb + tx];
    }
    __syncthreads();
    for (int q = 0; q < 16; ++q) {
        const int jj = q * 4 + ty;
        const int jglob = j0 + jj;
        const float scl = (jglob >= 256 && jglob < 512) ? QSCALE : 1.0f;
        const float val = tile[tx][jj] * scl;
        if (jglob < 1024) Wt1[jglob * 256 + k0 + tx] = f2bf(val);
        else              Wot[(jglob - 1024) * 256 + k0 + tx] = f2bf(val);
    }
}

// ---------------------------------------------------------------------------
// Kernel 1: fused gate+qkv projection GEMM, v9 (R11/R14 — frozen).
// ---------------------------------------------------------------------------
__global__ __launch_bounds__(256, 3) void k_qkvgate(
    const float* __restrict__ msa, const short* __restrict__ Wt1,
    short* __restrict__ gate, short* __restrict__ qb,
    short* __restrict__ kb, short* __restrict__ vb)
{
    __shared__ __align__(16) char Al[64 * 512];      // 32 KB; dead after hoist
    __shared__ __align__(16) short Bl[2][128 * 32];  // 2 x 8 KB double buffer
    const int tid = threadIdx.x;
    const int l = tid & 63, w = tid >> 6;
    const int wr = w >> 1, wc = w & 1;
    const int rowBase = blockIdx.x * 64;

    // stage A once: fp32 -> bf16 (16 iters, 64 rows)
    {
        const int arow0 = tid >> 6;          // 0..3
        const int col4  = (tid & 63) * 4;    // 0..252
        const int slot  = (tid & 63) >> 1;   // 16B slot 0..31
        const int sub   = (tid & 63) & 1;    // which 8B half
        for (int ii = 0; ii < 16; ++ii) {
            const int a_r = ii * 4 + arow0;
            const int i = rowBase + a_r;
            const int rr = i >> 8, ss = i & 255;
            fvec4 vv = *(const fvec4*)(msa + ((ss * R_DIM + rr) << 8) + col4);
            short4v b4;
            b4.x = f2bf(vv.x); b4.y = f2bf(vv.y);
            b4.z = f2bf(vv.z); b4.w = f2bf(vv.w);
            *(short4v*)(Al + a_r * 512 + ((slot ^ (a_r & 7)) << 4) + sub * 8) = b4;
        }
    }

    // B stage: tile tt covers cols [(tt>>3)*128,+128), k [(tt&7)*32,+32).
    auto stageB = [&](int tt, short* buf) {
        const int cb = (tt >> 3) * 128, k0 = (tt & 7) * 32;
        #pragma unroll
        for (int r = 0; r < 2; ++r) {
            const int L = r * 256 + w * 64 + l;
            const int row = L >> 2, psl = L & 3;
            const int gsl = psl ^ ((row >> 1) & 3);
            gload_lds16(Wt1 + (cb + row) * 256 + k0 + gsl * 8,
                        buf + (r * 256 + w * 64) * 8);
        }
    };

    stageB(0, (short*)Bl[0]);
    __syncthreads();   // drains the tile-0 DMA for ALL waves, then publishes

    // hoist ALL A fragments to registers (static indices only); Al dead after
    short8 af[8][2];
    #pragma unroll
    for (int kc = 0; kc < 8; ++kc) {
        const int aslot = kc * 4 + (l >> 4);
        #pragma unroll
        for (int it = 0; it < 2; ++it) {
            const int row = wr * 32 + it * 16 + (l & 15);
            af[kc][it] = *(const short8*)(Al + row * 512 + ((aslot ^ (row & 7)) << 4));
        }
    }

    short* AlT = (short*)Al;   // reuse as [128 jj][72 ss] bounce (18.4 KB)
    const int rr_blk = rowBase >> 8;
    const int ssBase = rowBase & 255;

    f32x4 acc[2][4] = {};
    for (int ct = 0; ct < 8; ++ct) {
        #pragma unroll
        for (int kc = 0; kc < 8; ++kc) {
            const int t = ct * 8 + kc;
            // issue next-tile DMA at the TOP (full step to fly)
            if (t + 1 < 64) stageB(t + 1, (short*)Bl[(kc + 1) & 1]);

            const short* Bb = (const short*)Bl[kc & 1];
            short8 bfr[4];
            #pragma unroll
            for (int jt = 0; jt < 4; ++jt) {
                const int row = wc * 64 + jt * 16 + (l & 15);
                const int psl = (l >> 4) ^ ((row >> 1) & 3);
                bfr[jt] = *(const short8*)(Bb + row * 32 + psl * 8);
            }
            #pragma unroll
            for (int it = 0; it < 2; ++it)
                #pragma unroll
                for (int jt = 0; jt < 4; ++jt)
                    acc[it][jt] = __builtin_amdgcn_mfma_f32_16x16x32_bf16(
                        af[kc][it], bfr[jt], acc[it][jt], 0, 0, 0);

            // vmcnt(0)+lgkmcnt(0)+barrier: cross-wave-safe publish
            __syncthreads();
        }
        const int colBase = ct * 128;
        const int sel = ct >> 1;  // 0 gate, 1 q, 2 k, 3 v
        if (sel < 3) {
            // gate/q/k epilogue: scatter to [p=(r*8+h)][s][c] (32B segments)
            short* dst = (sel == 0) ? gate : (sel == 1) ? qb : kb;
            #pragma unroll
            for (int it = 0; it < 2; ++it) {
                const int base_i = rowBase + wr * 32 + it * 16 + ((l >> 4) << 2);
                #pragma unroll
                for (int reg = 0; reg < 4; ++reg) {
                    const int i = base_i + reg;
                    const int rr = i >> 8, ss = i & 255;
                    #pragma unroll
                    for (int jt = 0; jt < 4; ++jt) {
                        const int jg = colBase + wc * 64 + jt * 16 + (l & 15);
                        const int jj = jg & 255;
                        const int h = jj >> 5, c = jj & 31;
                        float vv = acc[it][jt][reg];
                        if (sel == 0) vv = 1.0f / (1.0f + __builtin_amdgcn_exp2f(-vv * 1.4426950408889634f));
                        dst[(((rr << 3) + h) * 256 + ss) * 32 + c] = f2bf(vv);
                    }
                }
            }
        } else {
            // V epilogue: bounce-transpose through dead Al, then coalesced
            // [p][c][s] stores (16B contiguous per lane).
            const int jjBase = (colBase & 255);   // 0 or 128
            #pragma unroll
            for (int it = 0; it < 2; ++it) {
                const int ssL0 = wr * 32 + it * 16 + ((l >> 4) << 2);
                #pragma unroll
                for (int reg = 0; reg < 4; ++reg) {
                    #pragma unroll
                    for (int jt = 0; jt < 4; ++jt) {
                        const int jjL = wc * 64 + jt * 16 + (l & 15);
                        AlT[jjL * 72 + ssL0 + reg] = f2bf(acc[it][jt][reg]);
                    }
                }
            }
            __syncthreads();
            #pragma unroll
            for (int q = 0; q < 4; ++q) {
                const int cid = q * 256 + tid;     // 1024 16B-chunks
                const int jjL = cid >> 3, sc = cid & 7;
                short8 vv8 = *(const short8*)(&AlT[jjL * 72 + sc * 8]);
                const int jj = jjBase + jjL;
                const int h = jj >> 5, c = jj & 31;
                const int pp = (rr_blk << 3) + h;
                *(short8*)(vb + (pp << 13) + (c << 8) + ssBase + sc * 8) = vv8;
            }
            // next use of AlT is 8 barrier-separated steps away -> safe
        }
        #pragma unroll
        for (int it = 0; it < 2; ++it)
            #pragma unroll
            for (int jt = 0; jt < 4; ++jt)
                acc[it][jt] = (f32x4){0.f, 0.f, 0.f, 0.f};
    }
}

// ---------------------------------------------------------------------------
// Kernel 2: attention per (r,h), v4b — swapped QK + K=16 PV, ZERO LDS,
// ZERO cross-lane. st[it] = mfma_16x16x32(kf[jt], qf[it]) puts
// P^T[k=jt*16+g*4+reg][q=r] in lane (g=l>>4, r=l&15) — EXACTLY the
// A-fragment layout of the K=16 bf16 MFMA for the jt-th 16-k slice
// (A[q=l&15][k=g*4+e], e==reg). PV and row-sum run per-jt on K=16 MFMAs
// with pf = pack4(exp2(st)) — no LDS, no permute. B-operand = V from the
// [c][s] layout (8B contiguous/lane). oacc/ssum D-layouts identical to v2
// -> epilogue unchanged. Layout math re-verified after R15/R16.
// ---------------------------------------------------------------------------
__global__ __launch_bounds__(256) void k_attn(
    short* qo, const short* __restrict__ kb, const short* __restrict__ vb,
    const short* __restrict__ gate)
{
    const int tid = threadIdx.x;
    const int l = tid & 63, w = tid >> 6;
    const int p = blockIdx.x;
    short* qg = qo + p * 8192;
    const short* kg = kb + p * 8192;
    const short* vg = vb + p * 8192;   // [c][s] layout
    const short* gg = gate + p * 8192;
    const int r = l & 15, g = l >> 4;
    const int c0 = g * 8;

    // Q fragments (B-operand of swapped QK^T) straight from global
    short8 qf[4];
    #pragma unroll
    for (int it = 0; it < 4; ++it) {
        const int s = w * 64 + it * 16 + r;
        qf[it] = *(const short8*)(qg + s * 32 + c0);
    }

    f32x4 oacc[4][2] = {};
    f32x4 ssum[4] = {};
    short4v ones4;
    ones4.x = (short)0x3F80; ones4.y = (short)0x3F80;
    ones4.z = (short)0x3F80; ones4.w = (short)0x3F80;

    for (int ch = 0; ch < 4; ++ch) {
        const int j0 = ch * 64;
        // K fragments (A-operand of swapped QK^T) straight from global [s][c]
        short8 kf[4];
        #pragma unroll
        for (int jt = 0; jt < 4; ++jt) {
            const int row = j0 + jt * 16 + r;
            kf[jt] = *(const short8*)(kg + row * 32 + c0);
        }
        #pragma unroll
        for (int jt = 0; jt < 4; ++jt) {
            // swapped QK^T for this 16-k slice
            f32x4 st[4];
            #pragma unroll
            for (int it = 0; it < 4; ++it)
                st[it] = __builtin_amdgcn_mfma_f32_16x16x32_bf16(
                    kf[jt], qf[it], (f32x4){0.f, 0.f, 0.f, 0.f}, 0, 0, 0);
            // P fragment = exp2(st) packed to 4 bf16 (lane-local, e==reg)
            short4v pf[4];
            #pragma unroll
            for (int it = 0; it < 4; ++it) {
                const unsigned u0 =
                    (unsigned)(unsigned short)f2bf(__builtin_amdgcn_exp2f(st[it][0])) |
                    ((unsigned)(unsigned short)f2bf(__builtin_amdgcn_exp2f(st[it][1])) << 16);
                const unsigned u1 =
                    (unsigned)(unsigned short)f2bf(__builtin_amdgcn_exp2f(st[it][2])) |
                    ((unsigned)(unsigned short)f2bf(__builtin_amdgcn_exp2f(st[it][3])) << 16);
                i32x2 t; t.x = (int)u0; t.y = (int)u1;
                pf[it] = __builtin_bit_cast(short4v, t);
            }
            // V B-fragments for this 16-k slice: B[k=g*4..+4][col=c]
            short4v vf[2];
            #pragma unroll
            for (int cti = 0; cti < 2; ++cti)
                vf[cti] = *(const short4v*)(
                    vg + (cti * 16 + r) * 256 + j0 + jt * 16 + g * 4);
            // PV + row-sum on K=16 MFMAs
            #pragma unroll
            for (int it = 0; it < 4; ++it) {
                #pragma unroll
                for (int cti = 0; cti < 2; ++cti)
                    oacc[it][cti] = mfma16(pf[it], vf[cti], oacc[it][cti]);
                ssum[it] = mfma16(pf[it], ones4, ssum[it]);
            }
        }
    }
    // epilogue: normalize, gate, write in place over q (layouts same as v2)
    #pragma unroll
    for (int it = 0; it < 4; ++it) {
        #pragma unroll
        for (int reg = 0; reg < 4; ++reg) {
            const float inv = 1.0f / ssum[it][reg];
            const int s = w * 64 + it * 16 + (g << 2) + reg;
            #pragma unroll
            for (int cti = 0; cti < 2; ++cti) {
                const int c = cti * 16 + r;
                const float gv = bf2f(gg[s * 32 + c]);
                qg[s * 32 + c] = f2bf(oacc[it][cti][reg] * inv * gv);
            }
        }
    }
}

// ---------------------------------------------------------------------------
// Kernel 3: output projection GEMM + un-transpose, v2 (R14 — frozen).
// ---------------------------------------------------------------------------
__global__ __launch_bounds__(256, 4) void k_out(
    const short* __restrict__ ao, const short* __restrict__ Wot,
    float* __restrict__ out)
{
    __shared__ __align__(16) short Bl[2][128 * 32];  // 2 x 8 KB double buffer
    const int tid = threadIdx.x;
    const int l = tid & 63, w = tid >> 6;
    const int wr = w >> 1, wc = w & 1;
    const int rowBase = blockIdx.y * 128;
    const int colBase = blockIdx.x * 128;

    auto stageB = [&](int kc, short* buf) {
        const int k0 = kc * 32;
        #pragma unroll
        for (int r = 0; r < 2; ++r) {
            const int L = r * 256 + w * 64 + l;
            const int row = L >> 2, psl = L & 3;
            const int gsl = psl ^ ((row >> 1) & 3);
            gload_lds16(Wot + (colBase + row) * 256 + k0 + gsl * 8,
                        buf + (r * 256 + w * 64) * 8);
        }
    };

    stageB(0, (short*)Bl[0]);
    __syncthreads();   // drain own tile-0 DMA + publish

    f32x4 acc[4][4] = {};
    #pragma unroll
    for (int kc = 0; kc < 8; ++kc) {
        if (kc + 1 < 8) stageB(kc + 1, (short*)Bl[(kc + 1) & 1]);

        // A fragments direct from global: col jj = kc*32+(l>>4)*8 -> h=kc
        short8 af[4];
        #pragma unroll
        for (int it = 0; it < 4; ++it) {
            const int i = rowBase + wr * 64 + it * 16 + (l & 15);
            const int rr = i >> 8, ss = i & 255;
            af[it] = *(const short8*)(ao + (((rr << 3) + kc) * 256 + ss) * 32 + (l >> 4) * 8);
        }
        const short* Bb = (const short*)Bl[kc & 1];
        short8 bfr[4];
        #pragma unroll
        for (int jt = 0; jt < 4; ++jt) {
            const int row = wc * 64 + jt * 16 + (l & 15);
            const int psl = (l >> 4) ^ ((row >> 1) & 3);
            bfr[jt] = *(const short8*)(Bb + row * 32 + psl * 8);
        }
        #pragma unroll
        for (int it = 0; it < 4; ++it)
            #pragma unroll
            for (int jt = 0; jt < 4; ++jt)
                acc[it][jt] = __builtin_amdgcn_mfma_f32_16x16x32_bf16(
                    af[it], bfr[jt], acc[it][jt], 0, 0, 0);

        __syncthreads();   // vmcnt(0)+lgkmcnt(0)+barrier: race-free publish
    }
    #pragma unroll
    for (int it = 0; it < 4; ++it) {
        const int base_i = rowBase + wr * 64 + it * 16 + ((l >> 4) << 2);
        #pragma unroll
        for (int reg = 0; reg < 4; ++reg) {
            const int i = base_i + reg;
            const int rr = i >> 8, ss = i & 255;
            #pragma unroll
            for (int jt = 0; jt < 4; ++jt) {
                const int m = colBase + wc * 64 + jt * 16 + (l & 15);
                out[((ss * R_DIM + rr) << 8) + m] = acc[it][jt][reg];
            }
        }
    }
}

// ---------------------------------------------------------------------------
extern "C" void kernel_launch(void* const* d_in, const int* in_sizes, int n_in,
                              void* d_out, int out_size, void* d_ws, size_t ws_size,
                              hipStream_t stream) {
    const float* msa  = (const float*)d_in[0];
    const float* gp   = (const float*)d_in[1];
    const float* qkvp = (const float*)d_in[2];
    const float* op   = (const float*)d_in[3];
    float* out = (float*)d_out;
    char* ws = (char*)d_ws;

    const size_t SZ = 50331648;  // 98304*256*2 bytes (one bf16 activation tensor)
    short* Wt1  = (short*)ws;                        // 1024x256 bf16 (512 KB)
    short* Wot  = (short*)(ws + 524288);             // 256x256 bf16 (128 KB)
    short* gate = (short*)(ws + 655360);
    short* qb   = (short*)(ws + 655360 + 1 * SZ);
    short* kb   = (short*)(ws + 655360 + 2 * SZ);
    short* vb   = (short*)(ws + 655360 + 3 * SZ);

    k_prep<<<dim3(4, 20), 256, 0, stream>>>(gp, qkvp, op, Wt1, Wot);
    k_qkvgate<<<dim3(1536), 256, 0, stream>>>(msa, Wt1, gate, qb, kb, vb);
    k_attn<<<dim3(3072), 256, 0, stream>>>(qb, kb, vb, gate);
    k_out<<<dim3(2, 768), 256, 0, stream>>>(qb, Wot, out);
}

// Round 19
// 219.920 us; speedup vs baseline: 1.3038x; 1.0037x over previous
//
#include <hip/hip_runtime.h>
#include <hip/hip_bf16.h>

#define R_DIM 384
#define S_DIM 256
#define M_DIM 256

typedef __attribute__((ext_vector_type(4))) float  f32x4;
typedef __attribute__((ext_vector_type(4))) float  fvec4;
typedef __attribute__((ext_vector_type(8))) short  short8;
typedef __attribute__((ext_vector_type(4))) short  short4v;
typedef __attribute__((ext_vector_type(2))) int    i32x2;

__device__ __forceinline__ short f2bf(float f) {
    __hip_bfloat16 h = __float2bfloat16(f);
    return __builtin_bit_cast(short, h);
}
__device__ __forceinline__ float bf2f(short s) {
    return __bfloat162float(__builtin_bit_cast(__hip_bfloat16, s));
}

// K=16 bf16 MFMA: A/B = 4 bf16, C/D = 4 f32.
// A[row=l&15][k=(l>>4)*4+e], B[k=(l>>4)*4+e][col=l&15], D[row=(l>>4)*4+reg][col=l&15]
#if __has_builtin(__builtin_amdgcn_mfma_f32_16x16x16bf16_1k)
__device__ __forceinline__ f32x4 mfma16(short4v a, short4v b, f32x4 c) {
    return __builtin_amdgcn_mfma_f32_16x16x16bf16_1k(a, b, c, 0, 0, 0);
}
#else
__device__ __forceinline__ f32x4 mfma16(short4v a, short4v b, f32x4 c) {
    f32x4 d;
    asm volatile("v_mfma_f32_16x16x16_bf16 %0, %1, %2, %3\n\t"
                 "s_nop 7\n\ts_nop 7"
                 : "=&v"(d) : "v"(a), "v"(b), "v"(c));
    return d;
}
#endif

// async global->LDS, 16B per lane; LDS dest is wave-uniform base + lane*16
__device__ __forceinline__ void gload_lds16(const void* gsrc, void* ldst) {
    __builtin_amdgcn_global_load_lds(
        (const __attribute__((address_space(1))) unsigned int*)gsrc,
        (__attribute__((address_space(3))) unsigned int*)ldst, 16, 0, 0);
}

// SCALE * log2(e): folded into the q-columns of the fused weight so attention
// logits come out of MFMA already in log2 domain.
#define QSCALE (0.17677669529663687f * 1.4426950408889634f)

// ---------------------------------------------------------------------------
// Kernel 0: transpose + convert weights to bf16, k-contiguous rows.
// ---------------------------------------------------------------------------
__global__ __launch_bounds__(256) void k_prep(
    const float* __restrict__ gp, const float* __restrict__ qkvp,
    const float* __restrict__ op, short* __restrict__ Wt1,
    short* __restrict__ Wot)
{
    __shared__ float tile[64][65];
    const int tx = threadIdx.x & 63, ty = threadIdx.x >> 6;
    const int k0 = blockIdx.x * 64;     // 0..3
    const int j0 = blockIdx.y * 64;     // 0..19
    const float* src; int ld, cb;
    if (j0 < 256)       { src = gp;   ld = 256; cb = j0; }
    else if (j0 < 1024) { src = qkvp; ld = 768; cb = j0 - 256; }
    else                { src = op;   ld = 256; cb = j0 - 1024; }
    for (int q = 0; q < 16; ++q) {
        const int kk = q * 4 + ty;
        tile[kk][tx] = src[(k0 + kk) * ld + cb + tx];
    }
    __syncthreads();
    for (int q = 0; q < 16; ++q) {
        const int jj = q * 4 + ty;
        const int jglob = j0 + jj;
        const float scl = (jglob >= 256 && jglob < 512) ? QSCALE : 1.0f;
        const float val = tile[tx][jj] * scl;
        if (jglob < 1024) Wt1[jglob * 256 + k0 + tx] = f2bf(val);
        else              Wot[(jglob - 1024) * 256 + k0 + tx] = f2bf(val);
    }
}

// ---------------------------------------------------------------------------
// Kernel 1: fused gate+qkv projection GEMM, v9 (R11/R14/R17 — frozen local
// optimum). A-tile staged once to LDS -> af[8][2] register hoist; B dbuf via
// global_load_lds, stage-at-top / __syncthreads-at-bottom (race-free);
// V epilogue bounce-transposed through dead Al for coalesced [p][c][s]
// stores. Seven structural variants (R2,R5,R6,R12,R13,R18) all lost or
// raced — do not touch.
// ---------------------------------------------------------------------------
__global__ __launch_bounds__(256, 3) void k_qkvgate(
    const float* __restrict__ msa, const short* __restrict__ Wt1,
    short* __restrict__ gate, short* __restrict__ qb,
    short* __restrict__ kb, short* __restrict__ vb)
{
    __shared__ __align__(16) char Al[64 * 512];      // 32 KB; dead after hoist
    __shared__ __align__(16) short Bl[2][128 * 32];  // 2 x 8 KB double buffer
    const int tid = threadIdx.x;
    const int l = tid & 63, w = tid >> 6;
    const int wr = w >> 1, wc = w & 1;
    const int rowBase = blockIdx.x * 64;

    // stage A once: fp32 -> bf16 (16 iters, 64 rows)
    {
        const int arow0 = tid >> 6;          // 0..3
        const int col4  = (tid & 63) * 4;    // 0..252
        const int slot  = (tid & 63) >> 1;   // 16B slot 0..31
        const int sub   = (tid & 63) & 1;    // which 8B half
        for (int ii = 0; ii < 16; ++ii) {
            const int a_r = ii * 4 + arow0;
            const int i = rowBase + a_r;
            const int rr = i >> 8, ss = i & 255;
            fvec4 vv = *(const fvec4*)(msa + ((ss * R_DIM + rr) << 8) + col4);
            short4v b4;
            b4.x = f2bf(vv.x); b4.y = f2bf(vv.y);
            b4.z = f2bf(vv.z); b4.w = f2bf(vv.w);
            *(short4v*)(Al + a_r * 512 + ((slot ^ (a_r & 7)) << 4) + sub * 8) = b4;
        }
    }

    // B stage: tile tt covers cols [(tt>>3)*128,+128), k [(tt&7)*32,+32).
    auto stageB = [&](int tt, short* buf) {
        const int cb = (tt >> 3) * 128, k0 = (tt & 7) * 32;
        #pragma unroll
        for (int r = 0; r < 2; ++r) {
            const int L = r * 256 + w * 64 + l;
            const int row = L >> 2, psl = L & 3;
            const int gsl = psl ^ ((row >> 1) & 3);
            gload_lds16(Wt1 + (cb + row) * 256 + k0 + gsl * 8,
                        buf + (r * 256 + w * 64) * 8);
        }
    };

    stageB(0, (short*)Bl[0]);
    __syncthreads();   // drains the tile-0 DMA for ALL waves, then publishes

    // hoist ALL A fragments to registers (static indices only); Al dead after
    short8 af[8][2];
    #pragma unroll
    for (int kc = 0; kc < 8; ++kc) {
        const int aslot = kc * 4 + (l >> 4);
        #pragma unroll
        for (int it = 0; it < 2; ++it) {
            const int row = wr * 32 + it * 16 + (l & 15);
            af[kc][it] = *(const short8*)(Al + row * 512 + ((aslot ^ (row & 7)) << 4));
        }
    }

    short* AlT = (short*)Al;   // reuse as [128 jj][72 ss] bounce (18.4 KB)
    const int rr_blk = rowBase >> 8;
    const int ssBase = rowBase & 255;

    f32x4 acc[2][4] = {};
    for (int ct = 0; ct < 8; ++ct) {
        #pragma unroll
        for (int kc = 0; kc < 8; ++kc) {
            const int t = ct * 8 + kc;
            // issue next-tile DMA at the TOP (full step to fly)
            if (t + 1 < 64) stageB(t + 1, (short*)Bl[(kc + 1) & 1]);

            const short* Bb = (const short*)Bl[kc & 1];
            short8 bfr[4];
            #pragma unroll
            for (int jt = 0; jt < 4; ++jt) {
                const int row = wc * 64 + jt * 16 + (l & 15);
                const int psl = (l >> 4) ^ ((row >> 1) & 3);
                bfr[jt] = *(const short8*)(Bb + row * 32 + psl * 8);
            }
            #pragma unroll
            for (int it = 0; it < 2; ++it)
                #pragma unroll
                for (int jt = 0; jt < 4; ++jt)
                    acc[it][jt] = __builtin_amdgcn_mfma_f32_16x16x32_bf16(
                        af[kc][it], bfr[jt], acc[it][jt], 0, 0, 0);

            // vmcnt(0)+lgkmcnt(0)+barrier: cross-wave-safe publish
            __syncthreads();
        }
        const int colBase = ct * 128;
        const int sel = ct >> 1;  // 0 gate, 1 q, 2 k, 3 v
        if (sel < 3) {
            // gate/q/k epilogue: scatter to [p=(r*8+h)][s][c] (32B segments)
            short* dst = (sel == 0) ? gate : (sel == 1) ? qb : kb;
            #pragma unroll
            for (int it = 0; it < 2; ++it) {
                const int base_i = rowBase + wr * 32 + it * 16 + ((l >> 4) << 2);
                #pragma unroll
                for (int reg = 0; reg < 4; ++reg) {
                    const int i = base_i + reg;
                    const int rr = i >> 8, ss = i & 255;
                    #pragma unroll
                    for (int jt = 0; jt < 4; ++jt) {
                        const int jg = colBase + wc * 64 + jt * 16 + (l & 15);
                        const int jj = jg & 255;
                        const int h = jj >> 5, c = jj & 31;
                        float vv = acc[it][jt][reg];
                        if (sel == 0) vv = 1.0f / (1.0f + __builtin_amdgcn_exp2f(-vv * 1.4426950408889634f));
                        dst[(((rr << 3) + h) * 256 + ss) * 32 + c] = f2bf(vv);
                    }
                }
            }
        } else {
            // V epilogue: bounce-transpose through dead Al, then coalesced
            // [p][c][s] stores (16B contiguous per lane).
            const int jjBase = (colBase & 255);   // 0 or 128
            #pragma unroll
            for (int it = 0; it < 2; ++it) {
                const int ssL0 = wr * 32 + it * 16 + ((l >> 4) << 2);
                #pragma unroll
                for (int reg = 0; reg < 4; ++reg) {
                    #pragma unroll
                    for (int jt = 0; jt < 4; ++jt) {
                        const int jjL = wc * 64 + jt * 16 + (l & 15);
                        AlT[jjL * 72 + ssL0 + reg] = f2bf(acc[it][jt][reg]);
                    }
                }
            }
            __syncthreads();
            #pragma unroll
            for (int q = 0; q < 4; ++q) {
                const int cid = q * 256 + tid;     // 1024 16B-chunks
                const int jjL = cid >> 3, sc = cid & 7;
                short8 vv8 = *(const short8*)(&AlT[jjL * 72 + sc * 8]);
                const int jj = jjBase + jjL;
                const int h = jj >> 5, c = jj & 31;
                const int pp = (rr_blk << 3) + h;
                *(short8*)(vb + (pp << 13) + (c << 8) + ssBase + sc * 8) = vv8;
            }
            // next use of AlT is 8 barrier-separated steps away -> safe
        }
        #pragma unroll
        for (int it = 0; it < 2; ++it)
            #pragma unroll
            for (int jt = 0; jt < 4; ++jt)
                acc[it][jt] = (f32x4){0.f, 0.f, 0.f, 0.f};
    }
}

// ---------------------------------------------------------------------------
// Kernel 2: attention per (r,h), v4b (R17 — frozen). Swapped QK + K=16 PV,
// zero LDS, zero cross-lane.
// ---------------------------------------------------------------------------
__global__ __launch_bounds__(256) void k_attn(
    short* qo, const short* __restrict__ kb, const short* __restrict__ vb,
    const short* __restrict__ gate)
{
    const int tid = threadIdx.x;
    const int l = tid & 63, w = tid >> 6;
    const int p = blockIdx.x;
    short* qg = qo + p * 8192;
    const short* kg = kb + p * 8192;
    const short* vg = vb + p * 8192;   // [c][s] layout
    const short* gg = gate + p * 8192;
    const int r = l & 15, g = l >> 4;
    const int c0 = g * 8;

    short8 qf[4];
    #pragma unroll
    for (int it = 0; it < 4; ++it) {
        const int s = w * 64 + it * 16 + r;
        qf[it] = *(const short8*)(qg + s * 32 + c0);
    }

    f32x4 oacc[4][2] = {};
    f32x4 ssum[4] = {};
    short4v ones4;
    ones4.x = (short)0x3F80; ones4.y = (short)0x3F80;
    ones4.z = (short)0x3F80; ones4.w = (short)0x3F80;

    for (int ch = 0; ch < 4; ++ch) {
        const int j0 = ch * 64;
        short8 kf[4];
        #pragma unroll
        for (int jt = 0; jt < 4; ++jt) {
            const int row = j0 + jt * 16 + r;
            kf[jt] = *(const short8*)(kg + row * 32 + c0);
        }
        #pragma unroll
        for (int jt = 0; jt < 4; ++jt) {
            f32x4 st[4];
            #pragma unroll
            for (int it = 0; it < 4; ++it)
                st[it] = __builtin_amdgcn_mfma_f32_16x16x32_bf16(
                    kf[jt], qf[it], (f32x4){0.f, 0.f, 0.f, 0.f}, 0, 0, 0);
            short4v pf[4];
            #pragma unroll
            for (int it = 0; it < 4; ++it) {
                const unsigned u0 =
                    (unsigned)(unsigned short)f2bf(__builtin_amdgcn_exp2f(st[it][0])) |
                    ((unsigned)(unsigned short)f2bf(__builtin_amdgcn_exp2f(st[it][1])) << 16);
                const unsigned u1 =
                    (unsigned)(unsigned short)f2bf(__builtin_amdgcn_exp2f(st[it][2])) |
                    ((unsigned)(unsigned short)f2bf(__builtin_amdgcn_exp2f(st[it][3])) << 16);
                i32x2 t; t.x = (int)u0; t.y = (int)u1;
                pf[it] = __builtin_bit_cast(short4v, t);
            }
            short4v vf[2];
            #pragma unroll
            for (int cti = 0; cti < 2; ++cti)
                vf[cti] = *(const short4v*)(
                    vg + (cti * 16 + r) * 256 + j0 + jt * 16 + g * 4);
            #pragma unroll
            for (int it = 0; it < 4; ++it) {
                #pragma unroll
                for (int cti = 0; cti < 2; ++cti)
                    oacc[it][cti] = mfma16(pf[it], vf[cti], oacc[it][cti]);
                ssum[it] = mfma16(pf[it], ones4, ssum[it]);
            }
        }
    }
    #pragma unroll
    for (int it = 0; it < 4; ++it) {
        #pragma unroll
        for (int reg = 0; reg < 4; ++reg) {
            const float inv = 1.0f / ssum[it][reg];
            const int s = w * 64 + it * 16 + (g << 2) + reg;
            #pragma unroll
            for (int cti = 0; cti < 2; ++cti) {
                const int c = cti * 16 + r;
                const float gv = bf2f(gg[s * 32 + c]);
                qg[s * 32 + c] = f2bf(oacc[it][cti][reg] * inv * gv);
            }
        }
    }
}

// ---------------------------------------------------------------------------
// Kernel 3: output projection GEMM + un-transpose, v2 (R14 — frozen).
// ---------------------------------------------------------------------------
__global__ __launch_bounds__(256, 4) void k_out(
    const short* __restrict__ ao, const short* __restrict__ Wot,
    float* __restrict__ out)
{
    __shared__ __align__(16) short Bl[2][128 * 32];  // 2 x 8 KB double buffer
    const int tid = threadIdx.x;
    const int l = tid & 63, w = tid >> 6;
    const int wr = w >> 1, wc = w & 1;
    const int rowBase = blockIdx.y * 128;
    const int colBase = blockIdx.x * 128;

    auto stageB = [&](int kc, short* buf) {
        const int k0 = kc * 32;
        #pragma unroll
        for (int r = 0; r < 2; ++r) {
            const int L = r * 256 + w * 64 + l;
            const int row = L >> 2, psl = L & 3;
            const int gsl = psl ^ ((row >> 1) & 3);
            gload_lds16(Wot + (colBase + row) * 256 + k0 + gsl * 8,
                        buf + (r * 256 + w * 64) * 8);
        }
    };

    stageB(0, (short*)Bl[0]);
    __syncthreads();   // drain own tile-0 DMA + publish

    f32x4 acc[4][4] = {};
    #pragma unroll
    for (int kc = 0; kc < 8; ++kc) {
        if (kc + 1 < 8) stageB(kc + 1, (short*)Bl[(kc + 1) & 1]);

        short8 af[4];
        #pragma unroll
        for (int it = 0; it < 4; ++it) {
            const int i = rowBase + wr * 64 + it * 16 + (l & 15);
            const int rr = i >> 8, ss = i & 255;
            af[it] = *(const short8*)(ao + (((rr << 3) + kc) * 256 + ss) * 32 + (l >> 4) * 8);
        }
        const short* Bb = (const short*)Bl[kc & 1];
        short8 bfr[4];
        #pragma unroll
        for (int jt = 0; jt < 4; ++jt) {
            const int row = wc * 64 + jt * 16 + (l & 15);
            const int psl = (l >> 4) ^ ((row >> 1) & 3);
            bfr[jt] = *(const short8*)(Bb + row * 32 + psl * 8);
        }
        #pragma unroll
        for (int it = 0; it < 4; ++it)
            #pragma unroll
            for (int jt = 0; jt < 4; ++jt)
                acc[it][jt] = __builtin_amdgcn_mfma_f32_16x16x32_bf16(
                    af[it], bfr[jt], acc[it][jt], 0, 0, 0);

        __syncthreads();   // vmcnt(0)+lgkmcnt(0)+barrier: race-free publish
    }
    #pragma unroll
    for (int it = 0; it < 4; ++it) {
        const int base_i = rowBase + wr * 64 + it * 16 + ((l >> 4) << 2);
        #pragma unroll
        for (int reg = 0; reg < 4; ++reg) {
            const int i = base_i + reg;
            const int rr = i >> 8, ss = i & 255;
            #pragma unroll
            for (int jt = 0; jt < 4; ++jt) {
                const int m = colBase + wc * 64 + jt * 16 + (l & 15);
                out[((ss * R_DIM + rr) << 8) + m] = acc[it][jt][reg];
            }
        }
    }
}

// ---------------------------------------------------------------------------
extern "C" void kernel_launch(void* const* d_in, const int* in_sizes, int n_in,
                              void* d_out, int out_size, void* d_ws, size_t ws_size,
                              hipStream_t stream) {
    const float* msa  = (const float*)d_in[0];
    const float* gp   = (const float*)d_in[1];
    const float* qkvp = (const float*)d_in[2];
    const float* op   = (const float*)d_in[3];
    float* out = (float*)d_out;
    char* ws = (char*)d_ws;

    const size_t SZ = 50331648;  // 98304*256*2 bytes (one bf16 activation tensor)
    short* Wt1  = (short*)ws;                        // 1024x256 bf16 (512 KB)
    short* Wot  = (short*)(ws + 524288);             // 256x256 bf16 (128 KB)
    short* gate = (short*)(ws + 655360);
    short* qb   = (short*)(ws + 655360 + 1 * SZ);
    short* kb   = (short*)(ws + 655360 + 2 * SZ);
    short* vb   = (short*)(ws + 655360 + 3 * SZ);

    k_prep<<<dim3(4, 20), 256, 0, stream>>>(gp, qkvp, op, Wt1, Wot);
    k_qkvgate<<<dim3(1536), 256, 0, stream>>>(msa, Wt1, gate, qb, kb, vb);
    k_attn<<<dim3(3072), 256, 0, stream>>>(qb, kb, vb, gate);
    k_out<<<dim3(2, 768), 256, 0, stream>>>(qb, Wot, out);
}

// Round 20
// 209.259 us; speedup vs baseline: 1.3703x; 1.0509x over previous
//
#include <hip/hip_runtime.h>
#include <hip/hip_bf16.h>

#define R_DIM 384
#define S_DIM 256
#define M_DIM 256

typedef __attribute__((ext_vector_type(4))) float  f32x4;
typedef __attribute__((ext_vector_type(4))) float  fvec4;
typedef __attribute__((ext_vector_type(8))) short  short8;
typedef __attribute__((ext_vector_type(4))) short  short4v;
typedef __attribute__((ext_vector_type(2))) int    i32x2;

__device__ __forceinline__ short f2bf(float f) {
    __hip_bfloat16 h = __float2bfloat16(f);
    return __builtin_bit_cast(short, h);
}
__device__ __forceinline__ float bf2f(short s) {
    return __bfloat162float(__builtin_bit_cast(__hip_bfloat16, s));
}

// K=16 bf16 MFMA: A/B = 4 bf16, C/D = 4 f32.
// A[row=l&15][k=(l>>4)*4+e], B[k=(l>>4)*4+e][col=l&15], D[row=(l>>4)*4+reg][col=l&15]
#if __has_builtin(__builtin_amdgcn_mfma_f32_16x16x16bf16_1k)
__device__ __forceinline__ f32x4 mfma16(short4v a, short4v b, f32x4 c) {
    return __builtin_amdgcn_mfma_f32_16x16x16bf16_1k(a, b, c, 0, 0, 0);
}
#else
__device__ __forceinline__ f32x4 mfma16(short4v a, short4v b, f32x4 c) {
    f32x4 d;
    asm volatile("v_mfma_f32_16x16x16_bf16 %0, %1, %2, %3\n\t"
                 "s_nop 7\n\ts_nop 7"
                 : "=&v"(d) : "v"(a), "v"(b), "v"(c));
    return d;
}
#endif

// async global->LDS, 16B per lane; LDS dest is wave-uniform base + lane*16
__device__ __forceinline__ void gload_lds16(const void* gsrc, void* ldst) {
    __builtin_amdgcn_global_load_lds(
        (const __attribute__((address_space(1))) unsigned int*)gsrc,
        (__attribute__((address_space(3))) unsigned int*)ldst, 16, 0, 0);
}

// SCALE * log2(e): folded into the q-columns of the fused weight so attention
// logits come out of MFMA already in log2 domain.
#define QSCALE (0.17677669529663687f * 1.4426950408889634f)

// ---------------------------------------------------------------------------
// Kernel 0: transpose + convert weights to bf16, k-contiguous rows.
// ---------------------------------------------------------------------------
__global__ __launch_bounds__(256) void k_prep(
    const float* __restrict__ gp, const float* __restrict__ qkvp,
    const float* __restrict__ op, short* __restrict__ Wt1,
    short* __restrict__ Wot)
{
    __shared__ float tile[64][65];
    const int tx = threadIdx.x & 63, ty = threadIdx.x >> 6;
    const int k0 = blockIdx.x * 64;     // 0..3
    const int j0 = blockIdx.y * 64;     // 0..19
    const float* src; int ld, cb;
    if (j0 < 256)       { src = gp;   ld = 256; cb = j0; }
    else if (j0 < 1024) { src = qkvp; ld = 768; cb = j0 - 256; }
    else                { src = op;   ld = 256; cb = j0 - 1024; }
    for (int q = 0; q < 16; ++q) {
        const int kk = q * 4 + ty;
        tile[kk][tx] = src[(k0 + kk) * ld + cb + tx];
    }
    __syncthreads();
    for (int q = 0; q < 16; ++q) {
        const int jj = q * 4 + ty;
        const int jglob = j0 + jj;
        const float scl = (jglob >= 256 && jglob < 512) ? QSCALE : 1.0f;
        const float val = tile[tx][jj] * scl;
        if (jglob < 1024) Wt1[jglob * 256 + k0 + tx] = f2bf(val);
        else              Wot[(jglob - 1024) * 256 + k0 + tx] = f2bf(val);
    }
}

// ---------------------------------------------------------------------------
// Kernel 1: fused gate+qkv projection GEMM, v13 (2 K-tiles per barrier).
// v9 skeleton with the barrier count halved (64 -> 32): per iteration stage
// tiles t+2,t+3 into a 4-slot ring, consume tiles t,t+1 (16 MFMAs), ONE
// __syncthreads (vmcnt(0) drain = race-free publish; ring slot reuse is
// barrier-separated, twins stay lockstep — R18's drift bug cannot occur).
// A tile shrunk 32 -> 18.4 KB: staged in two 32-row halves through Ah
// (R18's verified sub-pattern), each wave hoists af[8][2] from its wr-half;
// Ah then doubles as the v9 V-bounce verbatim. LDS 51.2 KB -> 3 blocks/CU
// (occupancy-neutral vs v9).
// ---------------------------------------------------------------------------
__global__ __launch_bounds__(256, 3) void k_qkvgate(
    const float* __restrict__ msa, const short* __restrict__ Wt1,
    short* __restrict__ gate, short* __restrict__ qb,
    short* __restrict__ kb, short* __restrict__ vb)
{
    __shared__ __align__(16) short Ah[128 * 72];     // 18.4 KB: A halves + V bounce
    __shared__ __align__(16) short Bl[4][128 * 32];  // 4 x 8 KB ring
    const int tid = threadIdx.x;
    const int l = tid & 63, w = tid >> 6;
    const int wr = w >> 1, wc = w & 1;
    const int rowBase = blockIdx.x * 64;

    // B stage: tile tt covers cols [(tt>>3)*128,+128), k [(tt&7)*32,+32).
    auto stageB = [&](int tt, short* buf) {
        const int cb = (tt >> 3) * 128, k0 = (tt & 7) * 32;
        #pragma unroll
        for (int r = 0; r < 2; ++r) {
            const int L = r * 256 + w * 64 + l;
            const int row = L >> 2, psl = L & 3;
            const int gsl = psl ^ ((row >> 1) & 3);
            gload_lds16(Wt1 + (cb + row) * 256 + k0 + gsl * 8,
                        buf + (r * 256 + w * 64) * 8);
        }
    };

    stageB(0, (short*)Bl[0]);
    stageB(1, (short*)Bl[1]);

    // A staged in two 32-row halves through Ah (16 KB used); wave hoists
    // its fragments from the wr-matching half. The barriers also drain the
    // B prologue DMAs (vmcnt(0)) -> tiles 0,1 landed before the main loop.
    short8 af[8][2];
    for (int h = 0; h < 2; ++h) {
        {
            const int arow0 = tid >> 6;          // 0..3
            const int col4  = (tid & 63) * 4;    // 0..252
            const int slot  = (tid & 63) >> 1;   // 16B slot 0..31
            const int sub   = (tid & 63) & 1;    // which 8B half
            for (int ii = 0; ii < 8; ++ii) {
                const int a_r = ii * 4 + arow0;            // local 0..31
                const int i = rowBase + h * 32 + a_r;
                const int rr = i >> 8, ss = i & 255;
                fvec4 vv = *(const fvec4*)(msa + ((ss * R_DIM + rr) << 8) + col4);
                short4v b4;
                b4.x = f2bf(vv.x); b4.y = f2bf(vv.y);
                b4.z = f2bf(vv.z); b4.w = f2bf(vv.w);
                *(short4v*)((char*)Ah + a_r * 512 + ((slot ^ (a_r & 7)) << 4) + sub * 8) = b4;
            }
        }
        __syncthreads();
        if (wr == h) {
            #pragma unroll
            for (int kc = 0; kc < 8; ++kc) {
                const int aslot = kc * 4 + (l >> 4);
                #pragma unroll
                for (int it = 0; it < 2; ++it) {
                    const int row = it * 16 + (l & 15);    // local 0..31
                    af[kc][it] = *(const short8*)((char*)Ah + row * 512 +
                                                  ((aslot ^ (row & 7)) << 4));
                }
            }
        }
        __syncthreads();
    }

    short* AlT = (short*)Ah;   // V bounce [128 jj][72 ss] (18.4 KB)
    const int rr_blk = rowBase >> 8;
    const int ssBase = rowBase & 255;

    f32x4 acc[2][4] = {};
    for (int ct = 0; ct < 8; ++ct) {
        #pragma unroll
        for (int ip = 0; ip < 4; ++ip) {       // 2 tiles per barrier
            const int t0 = ct * 8 + ip * 2;
            // stage tiles t0+2, t0+3 (slots hold tiles read last iteration;
            // barrier-separated -> safe)
            if (t0 + 2 < 64) stageB(t0 + 2, (short*)Bl[(t0 + 2) & 3]);
            if (t0 + 3 < 64) stageB(t0 + 3, (short*)Bl[(t0 + 3) & 3]);

            #pragma unroll
            for (int u = 0; u < 2; ++u) {
                const int kc = ip * 2 + u;     // == (t0+u) & 7, static
                const short* Bb = (const short*)Bl[(t0 + u) & 3];
                short8 bfr[4];
                #pragma unroll
                for (int jt = 0; jt < 4; ++jt) {
                    const int row = wc * 64 + jt * 16 + (l & 15);
                    const int psl = (l >> 4) ^ ((row >> 1) & 3);
                    bfr[jt] = *(const short8*)(Bb + row * 32 + psl * 8);
                }
                #pragma unroll
                for (int it = 0; it < 2; ++it)
                    #pragma unroll
                    for (int jt = 0; jt < 4; ++jt)
                        acc[it][jt] = __builtin_amdgcn_mfma_f32_16x16x32_bf16(
                            af[kc][it], bfr[jt], acc[it][jt], 0, 0, 0);
            }
            // vmcnt(0)+lgkmcnt(0)+barrier: race-free publish (R11 invariant)
            __syncthreads();
        }
        const int colBase = ct * 128;
        const int sel = ct >> 1;  // 0 gate, 1 q, 2 k, 3 v
        if (sel < 3) {
            // gate/q/k epilogue: scatter to [p=(r*8+h)][s][c] (32B segments)
            short* dst = (sel == 0) ? gate : (sel == 1) ? qb : kb;
            #pragma unroll
            for (int it = 0; it < 2; ++it) {
                const int base_i = rowBase + wr * 32 + it * 16 + ((l >> 4) << 2);
                #pragma unroll
                for (int reg = 0; reg < 4; ++reg) {
                    const int i = base_i + reg;
                    const int rr = i >> 8, ss = i & 255;
                    #pragma unroll
                    for (int jt = 0; jt < 4; ++jt) {
                        const int jg = colBase + wc * 64 + jt * 16 + (l & 15);
                        const int jj = jg & 255;
                        const int h = jj >> 5, c = jj & 31;
                        float vv = acc[it][jt][reg];
                        if (sel == 0) vv = 1.0f / (1.0f + __builtin_amdgcn_exp2f(-vv * 1.4426950408889634f));
                        dst[(((rr << 3) + h) * 256 + ss) * 32 + c] = f2bf(vv);
                    }
                }
            }
        } else {
            // V epilogue: bounce-transpose through Ah, then coalesced
            // [p][c][s] stores (16B contiguous per lane). Ah writes are
            // barrier-separated from any other use (>=1 barrier between).
            const int jjBase = (colBase & 255);   // 0 or 128
            #pragma unroll
            for (int it = 0; it < 2; ++it) {
                const int ssL0 = wr * 32 + it * 16 + ((l >> 4) << 2);
                #pragma unroll
                for (int reg = 0; reg < 4; ++reg) {
                    #pragma unroll
                    for (int jt = 0; jt < 4; ++jt) {
                        const int jjL = wc * 64 + jt * 16 + (l & 15);
                        AlT[jjL * 72 + ssL0 + reg] = f2bf(acc[it][jt][reg]);
                    }
                }
            }
            __syncthreads();
            #pragma unroll
            for (int q = 0; q < 4; ++q) {
                const int cid = q * 256 + tid;     // 1024 16B-chunks
                const int jjL = cid >> 3, sc = cid & 7;
                short8 vv8 = *(const short8*)(&AlT[jjL * 72 + sc * 8]);
                const int jj = jjBase + jjL;
                const int h = jj >> 5, c = jj & 31;
                const int pp = (rr_blk << 3) + h;
                *(short8*)(vb + (pp << 13) + (c << 8) + ssBase + sc * 8) = vv8;
            }
        }
        #pragma unroll
        for (int it = 0; it < 2; ++it)
            #pragma unroll
            for (int jt = 0; jt < 4; ++jt)
                acc[it][jt] = (f32x4){0.f, 0.f, 0.f, 0.f};
    }
}

// ---------------------------------------------------------------------------
// Kernel 2: attention per (r,h), v4b (R17 — frozen). Swapped QK + K=16 PV,
// zero LDS, zero cross-lane.
// ---------------------------------------------------------------------------
__global__ __launch_bounds__(256) void k_attn(
    short* qo, const short* __restrict__ kb, const short* __restrict__ vb,
    const short* __restrict__ gate)
{
    const int tid = threadIdx.x;
    const int l = tid & 63, w = tid >> 6;
    const int p = blockIdx.x;
    short* qg = qo + p * 8192;
    const short* kg = kb + p * 8192;
    const short* vg = vb + p * 8192;   // [c][s] layout
    const short* gg = gate + p * 8192;
    const int r = l & 15, g = l >> 4;
    const int c0 = g * 8;

    short8 qf[4];
    #pragma unroll
    for (int it = 0; it < 4; ++it) {
        const int s = w * 64 + it * 16 + r;
        qf[it] = *(const short8*)(qg + s * 32 + c0);
    }

    f32x4 oacc[4][2] = {};
    f32x4 ssum[4] = {};
    short4v ones4;
    ones4.x = (short)0x3F80; ones4.y = (short)0x3F80;
    ones4.z = (short)0x3F80; ones4.w = (short)0x3F80;

    for (int ch = 0; ch < 4; ++ch) {
        const int j0 = ch * 64;
        short8 kf[4];
        #pragma unroll
        for (int jt = 0; jt < 4; ++jt) {
            const int row = j0 + jt * 16 + r;
            kf[jt] = *(const short8*)(kg + row * 32 + c0);
        }
        #pragma unroll
        for (int jt = 0; jt < 4; ++jt) {
            f32x4 st[4];
            #pragma unroll
            for (int it = 0; it < 4; ++it)
                st[it] = __builtin_amdgcn_mfma_f32_16x16x32_bf16(
                    kf[jt], qf[it], (f32x4){0.f, 0.f, 0.f, 0.f}, 0, 0, 0);
            short4v pf[4];
            #pragma unroll
            for (int it = 0; it < 4; ++it) {
                const unsigned u0 =
                    (unsigned)(unsigned short)f2bf(__builtin_amdgcn_exp2f(st[it][0])) |
                    ((unsigned)(unsigned short)f2bf(__builtin_amdgcn_exp2f(st[it][1])) << 16);
                const unsigned u1 =
                    (unsigned)(unsigned short)f2bf(__builtin_amdgcn_exp2f(st[it][2])) |
                    ((unsigned)(unsigned short)f2bf(__builtin_amdgcn_exp2f(st[it][3])) << 16);
                i32x2 t; t.x = (int)u0; t.y = (int)u1;
                pf[it] = __builtin_bit_cast(short4v, t);
            }
            short4v vf[2];
            #pragma unroll
            for (int cti = 0; cti < 2; ++cti)
                vf[cti] = *(const short4v*)(
                    vg + (cti * 16 + r) * 256 + j0 + jt * 16 + g * 4);
            #pragma unroll
            for (int it = 0; it < 4; ++it) {
                #pragma unroll
                for (int cti = 0; cti < 2; ++cti)
                    oacc[it][cti] = mfma16(pf[it], vf[cti], oacc[it][cti]);
                ssum[it] = mfma16(pf[it], ones4, ssum[it]);
            }
        }
    }
    #pragma unroll
    for (int it = 0; it < 4; ++it) {
        #pragma unroll
        for (int reg = 0; reg < 4; ++reg) {
            const float inv = 1.0f / ssum[it][reg];
            const int s = w * 64 + it * 16 + (g << 2) + reg;
            #pragma unroll
            for (int cti = 0; cti < 2; ++cti) {
                const int c = cti * 16 + r;
                const float gv = bf2f(gg[s * 32 + c]);
                qg[s * 32 + c] = f2bf(oacc[it][cti][reg] * inv * gv);
            }
        }
    }
}

// ---------------------------------------------------------------------------
// Kernel 3: output projection GEMM + un-transpose, v2 (R14 — frozen).
// ---------------------------------------------------------------------------
__global__ __launch_bounds__(256, 4) void k_out(
    const short* __restrict__ ao, const short* __restrict__ Wot,
    float* __restrict__ out)
{
    __shared__ __align__(16) short Bl[2][128 * 32];  // 2 x 8 KB double buffer
    const int tid = threadIdx.x;
    const int l = tid & 63, w = tid >> 6;
    const int wr = w >> 1, wc = w & 1;
    const int rowBase = blockIdx.y * 128;
    const int colBase = blockIdx.x * 128;

    auto stageB = [&](int kc, short* buf) {
        const int k0 = kc * 32;
        #pragma unroll
        for (int r = 0; r < 2; ++r) {
            const int L = r * 256 + w * 64 + l;
            const int row = L >> 2, psl = L & 3;
            const int gsl = psl ^ ((row >> 1) & 3);
            gload_lds16(Wot + (colBase + row) * 256 + k0 + gsl * 8,
                        buf + (r * 256 + w * 64) * 8);
        }
    };

    stageB(0, (short*)Bl[0]);
    __syncthreads();   // drain own tile-0 DMA + publish

    f32x4 acc[4][4] = {};
    #pragma unroll
    for (int kc = 0; kc < 8; ++kc) {
        if (kc + 1 < 8) stageB(kc + 1, (short*)Bl[(kc + 1) & 1]);

        short8 af[4];
        #pragma unroll
        for (int it = 0; it < 4; ++it) {
            const int i = rowBase + wr * 64 + it * 16 + (l & 15);
            const int rr = i >> 8, ss = i & 255;
            af[it] = *(const short8*)(ao + (((rr << 3) + kc) * 256 + ss) * 32 + (l >> 4) * 8);
        }
        const short* Bb = (const short*)Bl[kc & 1];
        short8 bfr[4];
        #pragma unroll
        for (int jt = 0; jt < 4; ++jt) {
            const int row = wc * 64 + jt * 16 + (l & 15);
            const int psl = (l >> 4) ^ ((row >> 1) & 3);
            bfr[jt] = *(const short8*)(Bb + row * 32 + psl * 8);
        }
        #pragma unroll
        for (int it = 0; it < 4; ++it)
            #pragma unroll
            for (int jt = 0; jt < 4; ++jt)
                acc[it][jt] = __builtin_amdgcn_mfma_f32_16x16x32_bf16(
                    af[it], bfr[jt], acc[it][jt], 0, 0, 0);

        __syncthreads();   // vmcnt(0)+lgkmcnt(0)+barrier: race-free publish
    }
    #pragma unroll
    for (int it = 0; it < 4; ++it) {
        const int base_i = rowBase + wr * 64 + it * 16 + ((l >> 4) << 2);
        #pragma unroll
        for (int reg = 0; reg < 4; ++reg) {
            const int i = base_i + reg;
            const int rr = i >> 8, ss = i & 255;
            #pragma unroll
            for (int jt = 0; jt < 4; ++jt) {
                const int m = colBase + wc * 64 + jt * 16 + (l & 15);
                out[((ss * R_DIM + rr) << 8) + m] = acc[it][jt][reg];
            }
        }
    }
}

// ---------------------------------------------------------------------------
extern "C" void kernel_launch(void* const* d_in, const int* in_sizes, int n_in,
                              void* d_out, int out_size, void* d_ws, size_t ws_size,
                              hipStream_t stream) {
    const float* msa  = (const float*)d_in[0];
    const float* gp   = (const float*)d_in[1];
    const float* qkvp = (const float*)d_in[2];
    const float* op   = (const float*)d_in[3];
    float* out = (float*)d_out;
    char* ws = (char*)d_ws;

    const size_t SZ = 50331648;  // 98304*256*2 bytes (one bf16 activation tensor)
    short* Wt1  = (short*)ws;                        // 1024x256 bf16 (512 KB)
    short* Wot  = (short*)(ws + 524288);             // 256x256 bf16 (128 KB)
    short* gate = (short*)(ws + 655360);
    short* qb   = (short*)(ws + 655360 + 1 * SZ);
    short* kb   = (short*)(ws + 655360 + 2 * SZ);
    short* vb   = (short*)(ws + 655360 + 3 * SZ);

    k_prep<<<dim3(4, 20), 256, 0, stream>>>(gp, qkvp, op, Wt1, Wot);
    k_qkvgate<<<dim3(1536), 256, 0, stream>>>(msa, Wt1, gate, qb, kb, vb);
    k_attn<<<dim3(3072), 256, 0, stream>>>(qb, kb, vb, gate);
    k_out<<<dim3(2, 768), 256, 0, stream>>>(qb, Wot, out);
}